// Round 1
// baseline (2058.267 us; speedup 1.0000x reference)
//
#include <hip/hip_runtime.h>
#include <math.h>

// Problem constants
#define BB 4
#define HH 64
#define WW2 64
#define DM 96
#define DN 192
#define KK 4
#define NN 16
#define RR 6
#define LL 4096
#define RN 38   // R + 2N

// Workspace layout (float offsets). Peak = 24,931,328 floats = 99.7 MB.
#define OFF_WBT_IN   0           // 96*384   transposed in-proj sign weights
#define OFF_WOUT_T   36864       // 192*96   transposed out-proj sign weights
#define OFF_WLB_T    55296       // 4*192*38 transposed x_dbl sign weights
#define OFF_WDB      84480       // 768*6    dts sign weights
#define OFF_WCS      89088       // 192*1728 conv sign weights (sc premultiplied)
#define OFF_XC       420864      // 3145728  xp transposed (B,Dn,L); reused as y accumulator
#define OFF_ZS       3566592     // 3145728  silu(z) in (B,L,Dn)
#define OFF_XCONV    6712320     // 3145728  conv output (B,Dn,L); reused as sign(y_ln*silu z)
#define OFF_XS       9858048     // 12582912 4-direction scan input; first 3145728 = sign image pre-conv
#define OFF_XSG      OFF_XS
#define OFF_XDBL     22440960    // 4*4*38*4096 x_dbl in (B,K,38,L)

__device__ __forceinline__ float fsign(float v) {
  return (v > 0.f) ? 1.f : ((v < 0.f) ? -1.f : 0.f);
}
__device__ __forceinline__ float softplusf(float v) {
  return fmaxf(v, 0.f) + log1pf(expf(-fabsf(v)));
}
__device__ __forceinline__ float siluf(float v) {
  return v / (1.f + expf(-v));
}
__device__ __forceinline__ float waveAllSum(float s) {
  #pragma unroll
  for (int off = 32; off; off >>= 1) s += __shfl_xor(s, off, 64);
  return s;
}

// ---------------- prep: all sign-weight transforms ----------------
__global__ __launch_bounds__(64) void k_prep(
    const float* __restrict__ W_in, const float* __restrict__ s_in,
    const float* __restrict__ W_out, const float* __restrict__ s_out,
    const float* __restrict__ Wl, const float* __restrict__ sl,
    const float* __restrict__ Wd, const float* __restrict__ sd,
    const float* __restrict__ convW, float* __restrict__ ws) {
  int r = blockIdx.x, lane = threadIdx.x;
  if (r < 384) {                       // W_in rows (len 96) -> WbT_in[c][r]
    const float* row = W_in + r * DM;
    float s = 0.f;
    for (int c = lane; c < DM; c += 64) s += row[c];
    s = waveAllSum(s);
    float mean = s / (float)DM, sc = s_in[r];
    float* WT = ws + OFF_WBT_IN;
    for (int c = lane; c < DM; c += 64) WT[c * 384 + r] = sc * fsign(row[c] - mean);
  } else if (r < 480) {                // W_out rows (len 192) -> WoutT[c][m]
    int m = r - 384;
    const float* row = W_out + m * DN;
    float s = 0.f;
    for (int c = lane; c < DN; c += 64) s += row[c];
    s = waveAllSum(s);
    float mean = s / (float)DN, sc = s_out[m];
    float* WT = ws + OFF_WOUT_T;
    for (int c = lane; c < DN; c += 64) WT[c * DM + m] = sc * fsign(row[c] - mean);
  } else if (r < 632) {                // Wl rows (len 192) -> WlbT[k][c][o]
    int idx = r - 480;
    const float* row = Wl + idx * DN;
    float s = 0.f;
    for (int c = lane; c < DN; c += 64) s += row[c];
    s = waveAllSum(s);
    float mean = s / (float)DN, sc = sl[idx];
    int k = idx / RN, o = idx % RN;
    float* WT = ws + OFF_WLB_T + k * (DN * RN);
    for (int c = lane; c < DN; c += 64) WT[c * RN + o] = sc * fsign(row[c] - mean);
  } else if (r < 1400) {               // Wd rows (len 6)
    int idx = r - 632;
    const float* row = Wd + idx * RR;
    float s = (lane < RR) ? row[lane] : 0.f;
    s = waveAllSum(s);
    float mean = s / (float)RR, sc = sd[idx];
    if (lane < RR) (ws + OFF_WDB)[idx * RR + lane] = sc * fsign(row[lane] - mean);
  } else {                             // conv rows (len 1728): sc = mean|W|, premultiplied
    int o = r - 1400;
    const float* row = convW + o * 1728;
    float s = 0.f;
    for (int j = lane; j < 1728; j += 64) s += fabsf(row[j]);
    s = waveAllSum(s);
    float sc = s / 1728.f;
    float* W = ws + OFF_WCS;
    for (int j = lane; j < 1728; j += 64) W[o * 1728 + j] = sc * fsign(row[j]);
  }
}

// ---------------- input bilinear: xz = sign(x) @ WbT + b ----------------
__global__ __launch_bounds__(384) void k_bilin_in(
    const float* __restrict__ x, const float* __restrict__ b_in,
    const float* __restrict__ ws, float* __restrict__ xc, float* __restrict__ zs) {
  __shared__ float sx[8 * DM];
  int p0 = blockIdx.x * 8;
  for (int i = threadIdx.x; i < 8 * DM; i += 384) sx[i] = fsign(x[p0 * DM + i]);
  __syncthreads();
  int o = threadIdx.x;
  const float* WT = ws + OFF_WBT_IN;
  float acc[8];
  float bias = b_in[o];
  #pragma unroll
  for (int i = 0; i < 8; ++i) acc[i] = bias;
  for (int c = 0; c < DM; ++c) {
    float w = WT[c * 384 + o];
    #pragma unroll
    for (int i = 0; i < 8; ++i) acc[i] += w * sx[i * DM + c];
  }
  int b = p0 >> 12, l0 = p0 & 4095;
  if (o < DN) {
    #pragma unroll
    for (int i = 0; i < 8; ++i) xc[(b * DN + o) * LL + l0 + i] = acc[i];
  } else {
    int oz = o - DN;
    #pragma unroll
    for (int i = 0; i < 8; ++i) zs[(p0 + i) * DN + oz] = siluf(acc[i]);
  }
}

// ---------------- sign image for conv input ----------------
__global__ __launch_bounds__(256) void k_sign(const float* __restrict__ xc,
                                              const float* __restrict__ move0,
                                              float* __restrict__ xsg) {
  int idx = blockIdx.x * 256 + threadIdx.x;
  int ch = (idx >> 12) % DN;
  xsg[idx] = fsign(xc[idx] + move0[ch]);
}

// ---------------- binary 3x3 conv + RPReLU + residual + SiLU ----------------
__global__ __launch_bounds__(256) void k_conv(
    const float* __restrict__ xsg, const float* __restrict__ xc,
    const float* __restrict__ ws, const float* __restrict__ conv_b,
    const float* __restrict__ rp_b0, const float* __restrict__ prelu_a,
    const float* __restrict__ rp_b1, float* __restrict__ xconv) {
  int b = blockIdx.x / DN, o = blockIdx.x % DN;
  int w = threadIdx.x & 63, hq = threadIdx.x >> 6;
  int hbase = hq * 16;
  const float* wrow = ws + OFF_WCS + o * 1728;
  const float* img = xsg + b * (DN * LL);
  float acc[16];
  #pragma unroll
  for (int j = 0; j < 16; ++j) acc[j] = 0.f;
  for (int ci = 0; ci < DN; ++ci) {
    float wr[9];
    #pragma unroll
    for (int j = 0; j < 9; ++j) wr[j] = wrow[ci * 9 + j];
    const float* p = img + ci * LL;
    #pragma unroll
    for (int jr = 0; jr < 18; ++jr) {
      int hr = hbase + jr - 1;
      bool okh = (hr >= 0) && (hr < 64);
      const float* pr = p + hr * 64 + w;
      float v0 = (okh && w > 0)  ? pr[-1] : 0.f;
      float v1 = okh             ? pr[0]  : 0.f;
      float v2 = (okh && w < 63) ? pr[1]  : 0.f;
      #pragma unroll
      for (int ky = 0; ky < 3; ++ky) {
        int j = jr - ky;
        if (j >= 0 && j < 16) {
          acc[j] += wr[ky * 3 + 0] * v0;
          acc[j] += wr[ky * 3 + 1] * v1;
          acc[j] += wr[ky * 3 + 2] * v2;
        }
      }
    }
  }
  float cb = conv_b[o] + rp_b0[o], pa = prelu_a[o], rb1 = rp_b1[o];
  const float* xcp = xc + (b * DN + o) * LL;
  float* xop = xconv + (b * DN + o) * LL;
  #pragma unroll
  for (int j = 0; j < 16; ++j) {
    int h = hbase + j;
    float t = acc[j] + cb;
    t = (t >= 0.f) ? t : pa * t;
    t += rb1 + xcp[h * 64 + w];
    xop[h * 64 + w] = siluf(t);
  }
}

// ---------------- build 4-direction scan input xs ----------------
__global__ __launch_bounds__(256) void k_build_xs(const float* __restrict__ xconv,
                                                  float* __restrict__ xs) {
  int idx = blockIdx.x * 256 + threadIdx.x;
  int l = idx & 4095;
  int d = (idx >> 12) % DN;
  int k = ((idx >> 12) / DN) % KK;
  int b = idx / (KK * DN * LL);
  int src;
  if (k == 0)      src = l;
  else if (k == 1) src = ((l & 63) << 6) | (l >> 6);
  else if (k == 2) src = 4095 - l;
  else { int t2 = 4095 - l; src = ((t2 & 63) << 6) | (t2 >> 6); }
  xs[idx] = xconv[(b * DN + d) * LL + src];
}

// ---------------- x_dbl bilinear: rows are raw 192-chunks of xs ----------------
__global__ __launch_bounds__(256) void k_xdbl(
    const float* __restrict__ xs, const float* __restrict__ ws,
    const float* __restrict__ bl, float* __restrict__ xdbl) {
  __shared__ float ssx[32 * DN];
  int bk = blockIdx.x >> 7;
  int l0 = (blockIdx.x & 127) << 5;
  int k = bk & 3;
  const float* base = xs + (size_t)bk * (DN * LL) + (size_t)l0 * DN;
  for (int i = threadIdx.x; i < 32 * DN; i += 256) ssx[i] = fsign(base[i]);
  __syncthreads();
  const float* WT = ws + OFF_WLB_T + k * (DN * RN);
  for (int oi = threadIdx.x; oi < 32 * RN; oi += 256) {
    int lr = oi / RN, o = oi % RN;
    float acc = bl[k * RN + o];
    const float* sx = ssx + lr * DN;
    for (int c = 0; c < DN; ++c) acc += sx[c] * WT[c * RN + o];
    xdbl[(bk * RN + o) * LL + l0 + lr] = acc;
  }
}

// ---------------- selective scan, fused dts-bilinear + softplus, fused y-combine ----------------
__global__ __launch_bounds__(256) void k_scan(
    const float* __restrict__ xs, const float* __restrict__ xdbl,
    const float* __restrict__ ws, const float* __restrict__ bd,
    const float* __restrict__ dt_bias, const float* __restrict__ A_logs,
    const float* __restrict__ Ds, float* __restrict__ y) {
  int bk = blockIdx.x / 12;      // b*4+k
  int dc = blockIdx.x % 12;
  int k = bk & 3;
  int d0 = dc * 16;
  int g = threadIdx.x >> 4;      // channel within block
  int n = threadIdx.x & 15;
  int d = d0 + g;
  float An = -expf(A_logs[(k * DN + d) * NN + n]);
  float Dd = Ds[k * DN + d];
  float h = 0.f;
  __shared__ float Bt[64 * 17], Ct[64 * 17], del[16 * 65], uu[16 * 65], sdt[384];
  const float* Bp = xdbl + (bk * RN + RR) * LL;
  const float* Cp = xdbl + (bk * RN + RR + NN) * LL;
  const float* dtsrc = xdbl + bk * (RN * LL);     // rows 0..5 are dts_r
  const float* up = xs + (size_t)(bk * DN + d0) * LL;
  float* yb = y + ((bk >> 2) * DN + d) * LL;
  for (int t0 = 0; t0 < LL; t0 += 64) {
    __syncthreads();
    // stage signs for the fused dts bilinear (raw reshape: flat index t*6+r)
    for (int i = threadIdx.x; i < 384; i += 256) {
      int f = t0 * RR + i;
      sdt[i] = fsign(dtsrc[(f >> 12) * LL + (f & 4095)]);
    }
    for (int i = threadIdx.x; i < 1024; i += 256) {
      int ni = i >> 6, ti = i & 63;
      Bt[ti * 17 + ni] = Bp[ni * LL + t0 + ti];
      Ct[ti * 17 + ni] = Cp[ni * LL + t0 + ti];
      uu[ni * 65 + ti] = up[(size_t)ni * LL + t0 + ti];
    }
    __syncthreads();
    // compute delta for the 16 channels of this block over 64 steps
    for (int i = threadIdx.x; i < 1024; i += 256) {
      int gi = i >> 6, ti = i & 63;
      int dd = d0 + gi;
      const float* wr = ws + OFF_WDB + (k * DN + dd) * RR;
      float acc = bd[k * DN + dd] + dt_bias[k * DN + dd];
      #pragma unroll
      for (int r = 0; r < RR; ++r) acc += sdt[ti * RR + r] * wr[r];
      del[gi * 65 + ti] = softplusf(acc);
    }
    __syncthreads();
    for (int t = 0; t < 64; ++t) {
      float bn = Bt[t * 17 + n], cn = Ct[t * 17 + n];
      float dv = del[g * 65 + t], uv = uu[g * 65 + t];
      float a = expf(dv * An);
      h = a * h + (dv * uv) * bn;
      float yp = h * cn;
      yp += __shfl_xor(yp, 1, 16);
      yp += __shfl_xor(yp, 2, 16);
      yp += __shfl_xor(yp, 4, 16);
      yp += __shfl_xor(yp, 8, 16);
      if (n == 0) {
        int ta = t0 + t, l;
        if (k == 0)      l = ta;
        else if (k == 1) l = ((ta & 63) << 6) | (ta >> 6);
        else if (k == 2) l = 4095 - ta;
        else { int t2 = 4095 - ta; l = ((t2 & 63) << 6) | (t2 >> 6); }
        atomicAdd(&yb[l], yp + Dd * uv);
      }
    }
  }
}

// ---------------- LayerNorm over Dn + * silu(z) + sign ----------------
__global__ __launch_bounds__(256) void k_ln(
    const float* __restrict__ y, const float* __restrict__ zs,
    const float* __restrict__ ln_w, const float* __restrict__ ln_b,
    float* __restrict__ ybuf) {
  __shared__ float ty[DN * 65];
  __shared__ float ps[256];
  __shared__ float smu[64], srs[64];
  int b = blockIdx.x >> 6;
  int l0 = (blockIdx.x & 63) << 6;
  for (int i = threadIdx.x; i < DN * 64; i += 256) {
    int d = i >> 6, lc = i & 63;
    ty[d * 65 + lc] = y[(b * DN + d) * LL + l0 + lc];
  }
  __syncthreads();
  int lc = threadIdx.x & 63, part = threadIdx.x >> 6;
  float s = 0.f;
  for (int d = part * 48; d < part * 48 + 48; ++d) s += ty[d * 65 + lc];
  ps[threadIdx.x] = s;
  __syncthreads();
  if (threadIdx.x < 64)
    smu[threadIdx.x] = (ps[threadIdx.x] + ps[threadIdx.x + 64] +
                        ps[threadIdx.x + 128] + ps[threadIdx.x + 192]) / (float)DN;
  __syncthreads();
  float mu = smu[lc];
  float q = 0.f;
  for (int d = part * 48; d < part * 48 + 48; ++d) {
    float v = ty[d * 65 + lc] - mu; q += v * v;
  }
  ps[threadIdx.x] = q;
  __syncthreads();
  if (threadIdx.x < 64) {
    float var = (ps[threadIdx.x] + ps[threadIdx.x + 64] +
                 ps[threadIdx.x + 128] + ps[threadIdx.x + 192]) / (float)DN;
    srs[threadIdx.x] = rsqrtf(var + 1e-5f);
  }
  __syncthreads();
  for (int i = threadIdx.x; i < 64 * DN; i += 256) {
    int lc2 = i / DN, d = i % DN;
    float v = ty[d * 65 + lc2];
    float ln = (v - smu[lc2]) * srs[lc2] * ln_w[d] + ln_b[d];
    float sz = zs[(b * LL + l0 + lc2) * DN + d];
    ybuf[(b * LL + l0 + lc2) * DN + d] = fsign(ln * sz);
  }
}

// ---------------- output bilinear ----------------
__global__ __launch_bounds__(256) void k_out(
    const float* __restrict__ ybuf, const float* __restrict__ ws,
    const float* __restrict__ b_out, float* __restrict__ out) {
  __shared__ float ssy[16 * DN];
  int p0 = blockIdx.x * 16;
  for (int i = threadIdx.x; i < 16 * DN; i += 256) ssy[i] = ybuf[p0 * DN + i];
  __syncthreads();
  const float* WT = ws + OFF_WOUT_T;
  for (int oi = threadIdx.x; oi < 16 * DM; oi += 256) {
    int pr = oi / DM, m = oi % DM;
    float acc = b_out[m];
    const float* sy = ssy + pr * DN;
    for (int c = 0; c < DN; ++c) acc += sy[c] * WT[c * DM + m];
    out[(p0 + pr) * DM + m] = acc;
  }
}

extern "C" void kernel_launch(void* const* d_in, const int* in_sizes, int n_in,
                              void* d_out, int out_size, void* d_ws, size_t ws_size,
                              hipStream_t stream) {
  const float* x       = (const float*)d_in[0];
  const float* W_in    = (const float*)d_in[1];
  const float* b_in    = (const float*)d_in[2];
  const float* s_in    = (const float*)d_in[3];
  const float* move0_b = (const float*)d_in[4];
  const float* conv_W  = (const float*)d_in[5];
  const float* conv_b  = (const float*)d_in[6];
  const float* rp_b0   = (const float*)d_in[7];
  const float* prelu_a = (const float*)d_in[8];
  const float* rp_b1   = (const float*)d_in[9];
  const float* Wl      = (const float*)d_in[10];
  const float* bl      = (const float*)d_in[11];
  const float* sl      = (const float*)d_in[12];
  const float* Wd      = (const float*)d_in[13];
  const float* bd      = (const float*)d_in[14];
  const float* sd      = (const float*)d_in[15];
  const float* dt_bias = (const float*)d_in[16];
  const float* A_logs  = (const float*)d_in[17];
  const float* Ds      = (const float*)d_in[18];
  const float* ln_w    = (const float*)d_in[19];
  const float* ln_b    = (const float*)d_in[20];
  const float* W_out   = (const float*)d_in[21];
  const float* b_out   = (const float*)d_in[22];
  const float* s_out   = (const float*)d_in[23];
  float* ws  = (float*)d_ws;
  float* out = (float*)d_out;

  hipLaunchKernelGGL(k_prep, dim3(1592), dim3(64), 0, stream,
                     W_in, s_in, W_out, s_out, Wl, sl, Wd, sd, conv_W, ws);
  hipLaunchKernelGGL(k_bilin_in, dim3(2048), dim3(384), 0, stream,
                     x, b_in, ws, ws + OFF_XC, ws + OFF_ZS);
  hipLaunchKernelGGL(k_sign, dim3(12288), dim3(256), 0, stream,
                     ws + OFF_XC, move0_b, ws + OFF_XSG);
  hipLaunchKernelGGL(k_conv, dim3(768), dim3(256), 0, stream,
                     ws + OFF_XSG, ws + OFF_XC, ws, conv_b, rp_b0, prelu_a, rp_b1,
                     ws + OFF_XCONV);
  hipLaunchKernelGGL(k_build_xs, dim3(49152), dim3(256), 0, stream,
                     ws + OFF_XCONV, ws + OFF_XS);
  hipLaunchKernelGGL(k_xdbl, dim3(2048), dim3(256), 0, stream,
                     ws + OFF_XS, ws, bl, ws + OFF_XDBL);
  // y accumulator (aliases xc, dead after k_conv)
  hipMemsetAsync((void*)(ws + OFF_XC), 0, (size_t)3145728 * sizeof(float), stream);
  hipLaunchKernelGGL(k_scan, dim3(192), dim3(256), 0, stream,
                     ws + OFF_XS, ws + OFF_XDBL, ws, bd, dt_bias, A_logs, Ds,
                     ws + OFF_XC);
  hipLaunchKernelGGL(k_ln, dim3(256), dim3(256), 0, stream,
                     ws + OFF_XC, ws + OFF_ZS, ln_w, ln_b, ws + OFF_XCONV);
  hipLaunchKernelGGL(k_out, dim3(1024), dim3(256), 0, stream,
                     ws + OFF_XCONV, ws, b_out, out);
}

// Round 2
// 891.670 us; speedup vs baseline: 2.3083x; 2.3083x over previous
//
#include <hip/hip_runtime.h>
#include <math.h>

// Problem constants
#define BB 4
#define HH 64
#define WW2 64
#define DM 96
#define DN 192
#define KK 4
#define NN 16
#define RR 6
#define LL 4096
#define RN 38   // R + 2N

#define LOG2E 1.4426950408889634f
#define LN2   0.6931471805599453f

// Workspace layout (float offsets). Peak = 24,931,328 floats = 99.7 MB.
#define OFF_WBT_IN   0           // 96*384   transposed in-proj sign weights
#define OFF_WOUT_T   36864       // 192*96   transposed out-proj sign weights
#define OFF_WLB_T    55296       // 4*192*38 transposed x_dbl sign weights
#define OFF_WDB      84480       // 768*6    dts sign weights
#define OFF_WCS      89088       // 192*1728 conv sign weights; reused as Ssum (196608) by scan
#define OFF_XC       420864      // 3145728  xp transposed (B,Dn,L); reused as y accumulator [b][L][d]
#define OFF_ZS       3566592     // 3145728  silu(z) in (B,L,Dn)
#define OFF_XCONV    6712320     // 3145728  conv out (B,Dn,L); reused as hend/h0 [c][bkd][n]; then ybuf
#define OFF_XS       9858048     // 12582912 4-direction scan input; first 3145728 = sign image pre-conv
#define OFF_XSG      OFF_XS
#define OFF_XDBL     22440960    // 4*4*38*4096 x_dbl in (B,K,38,L)
#define OFF_HEND     OFF_XCONV
#define OFF_SSUM     OFF_WCS

__device__ __forceinline__ float fsign(float v) {
  return (v > 0.f) ? 1.f : ((v < 0.f) ? -1.f : 0.f);
}
__device__ __forceinline__ float softplusf(float v) {
  return fmaxf(v, 0.f) + LN2 * log2f(1.f + exp2f(-fabsf(v) * LOG2E));
}
__device__ __forceinline__ float siluf(float v) {
  return v / (1.f + expf(-v));
}
__device__ __forceinline__ float waveAllSum(float s) {
  #pragma unroll
  for (int off = 32; off; off >>= 1) s += __shfl_xor(s, off, 64);
  return s;
}

// ---------------- prep: all sign-weight transforms ----------------
__global__ __launch_bounds__(64) void k_prep(
    const float* __restrict__ W_in, const float* __restrict__ s_in,
    const float* __restrict__ W_out, const float* __restrict__ s_out,
    const float* __restrict__ Wl, const float* __restrict__ sl,
    const float* __restrict__ Wd, const float* __restrict__ sd,
    const float* __restrict__ convW, float* __restrict__ ws) {
  int r = blockIdx.x, lane = threadIdx.x;
  if (r < 384) {
    const float* row = W_in + r * DM;
    float s = 0.f;
    for (int c = lane; c < DM; c += 64) s += row[c];
    s = waveAllSum(s);
    float mean = s / (float)DM, sc = s_in[r];
    float* WT = ws + OFF_WBT_IN;
    for (int c = lane; c < DM; c += 64) WT[c * 384 + r] = sc * fsign(row[c] - mean);
  } else if (r < 480) {
    int m = r - 384;
    const float* row = W_out + m * DN;
    float s = 0.f;
    for (int c = lane; c < DN; c += 64) s += row[c];
    s = waveAllSum(s);
    float mean = s / (float)DN, sc = s_out[m];
    float* WT = ws + OFF_WOUT_T;
    for (int c = lane; c < DN; c += 64) WT[c * DM + m] = sc * fsign(row[c] - mean);
  } else if (r < 632) {
    int idx = r - 480;
    const float* row = Wl + idx * DN;
    float s = 0.f;
    for (int c = lane; c < DN; c += 64) s += row[c];
    s = waveAllSum(s);
    float mean = s / (float)DN, sc = sl[idx];
    int k = idx / RN, o = idx % RN;
    float* WT = ws + OFF_WLB_T + k * (DN * RN);
    for (int c = lane; c < DN; c += 64) WT[c * RN + o] = sc * fsign(row[c] - mean);
  } else if (r < 1400) {
    int idx = r - 632;
    const float* row = Wd + idx * RR;
    float s = (lane < RR) ? row[lane] : 0.f;
    s = waveAllSum(s);
    float mean = s / (float)RR, sc = sd[idx];
    if (lane < RR) (ws + OFF_WDB)[idx * RR + lane] = sc * fsign(row[lane] - mean);
  } else {
    int o = r - 1400;
    const float* row = convW + o * 1728;
    float s = 0.f;
    for (int j = lane; j < 1728; j += 64) s += fabsf(row[j]);
    s = waveAllSum(s);
    float sc = s / 1728.f;
    float* W = ws + OFF_WCS;
    for (int j = lane; j < 1728; j += 64) W[o * 1728 + j] = sc * fsign(row[j]);
  }
}

// ---------------- input bilinear: xz = sign(x) @ WbT + b ----------------
__global__ __launch_bounds__(384) void k_bilin_in(
    const float* __restrict__ x, const float* __restrict__ b_in,
    const float* __restrict__ ws, float* __restrict__ xc, float* __restrict__ zs) {
  __shared__ float sx[8 * DM];
  int p0 = blockIdx.x * 8;
  for (int i = threadIdx.x; i < 8 * DM; i += 384) sx[i] = fsign(x[p0 * DM + i]);
  __syncthreads();
  int o = threadIdx.x;
  const float* WT = ws + OFF_WBT_IN;
  float acc[8];
  float bias = b_in[o];
  #pragma unroll
  for (int i = 0; i < 8; ++i) acc[i] = bias;
  for (int c = 0; c < DM; ++c) {
    float w = WT[c * 384 + o];
    #pragma unroll
    for (int i = 0; i < 8; ++i) acc[i] += w * sx[i * DM + c];
  }
  int b = p0 >> 12, l0 = p0 & 4095;
  if (o < DN) {
    #pragma unroll
    for (int i = 0; i < 8; ++i) xc[(b * DN + o) * LL + l0 + i] = acc[i];
  } else {
    int oz = o - DN;
    #pragma unroll
    for (int i = 0; i < 8; ++i) zs[(p0 + i) * DN + oz] = siluf(acc[i]);
  }
}

// ---------------- sign image for conv input ----------------
__global__ __launch_bounds__(256) void k_sign(const float* __restrict__ xc,
                                              const float* __restrict__ move0,
                                              float* __restrict__ xsg) {
  int idx = blockIdx.x * 256 + threadIdx.x;
  int ch = (idx >> 12) % DN;
  xsg[idx] = fsign(xc[idx] + move0[ch]);
}

// ---------------- binary 3x3 conv + RPReLU + residual + SiLU ----------------
__global__ __launch_bounds__(256) void k_conv(
    const float* __restrict__ xsg, const float* __restrict__ xc,
    const float* __restrict__ ws, const float* __restrict__ conv_b,
    const float* __restrict__ rp_b0, const float* __restrict__ prelu_a,
    const float* __restrict__ rp_b1, float* __restrict__ xconv) {
  int b = blockIdx.x / DN, o = blockIdx.x % DN;
  int w = threadIdx.x & 63, hq = threadIdx.x >> 6;
  int hbase = hq * 16;
  const float* wrow = ws + OFF_WCS + o * 1728;
  const float* img = xsg + b * (DN * LL);
  float acc[16];
  #pragma unroll
  for (int j = 0; j < 16; ++j) acc[j] = 0.f;
  for (int ci = 0; ci < DN; ++ci) {
    float wr[9];
    #pragma unroll
    for (int j = 0; j < 9; ++j) wr[j] = wrow[ci * 9 + j];
    const float* p = img + ci * LL;
    #pragma unroll
    for (int jr = 0; jr < 18; ++jr) {
      int hr = hbase + jr - 1;
      bool okh = (hr >= 0) && (hr < 64);
      const float* pr = p + hr * 64 + w;
      float v0 = (okh && w > 0)  ? pr[-1] : 0.f;
      float v1 = okh             ? pr[0]  : 0.f;
      float v2 = (okh && w < 63) ? pr[1]  : 0.f;
      #pragma unroll
      for (int ky = 0; ky < 3; ++ky) {
        int j = jr - ky;
        if (j >= 0 && j < 16) {
          acc[j] += wr[ky * 3 + 0] * v0;
          acc[j] += wr[ky * 3 + 1] * v1;
          acc[j] += wr[ky * 3 + 2] * v2;
        }
      }
    }
  }
  float cb = conv_b[o] + rp_b0[o], pa = prelu_a[o], rb1 = rp_b1[o];
  const float* xcp = xc + (b * DN + o) * LL;
  float* xop = xconv + (b * DN + o) * LL;
  #pragma unroll
  for (int j = 0; j < 16; ++j) {
    int h = hbase + j;
    float t = acc[j] + cb;
    t = (t >= 0.f) ? t : pa * t;
    t += rb1 + xcp[h * 64 + w];
    xop[h * 64 + w] = siluf(t);
  }
}

// ---------------- build 4-direction scan input xs ----------------
__global__ __launch_bounds__(256) void k_build_xs(const float* __restrict__ xconv,
                                                  float* __restrict__ xs) {
  int idx = blockIdx.x * 256 + threadIdx.x;
  int l = idx & 4095;
  int d = (idx >> 12) % DN;
  int k = ((idx >> 12) / DN) % KK;
  int b = idx / (KK * DN * LL);
  int src;
  if (k == 0)      src = l;
  else if (k == 1) src = ((l & 63) << 6) | (l >> 6);
  else if (k == 2) src = 4095 - l;
  else { int t2 = 4095 - l; src = ((t2 & 63) << 6) | (t2 >> 6); }
  xs[idx] = xconv[(b * DN + d) * LL + src];
}

// ---------------- x_dbl bilinear ----------------
__global__ __launch_bounds__(256) void k_xdbl(
    const float* __restrict__ xs, const float* __restrict__ ws,
    const float* __restrict__ bl, float* __restrict__ xdbl) {
  __shared__ float ssx[32 * DN];
  int bk = blockIdx.x >> 7;
  int l0 = (blockIdx.x & 127) << 5;
  int k = bk & 3;
  const float* base = xs + (size_t)bk * (DN * LL) + (size_t)l0 * DN;
  for (int i = threadIdx.x; i < 32 * DN; i += 256) ssx[i] = fsign(base[i]);
  __syncthreads();
  const float* WT = ws + OFF_WLB_T + k * (DN * RN);
  for (int oi = threadIdx.x; oi < 32 * RN; oi += 256) {
    int lr = oi / RN, o = oi % RN;
    float acc = bl[k * RN + o];
    const float* sx = ssx + lr * DN;
    for (int c = 0; c < DN; ++c) acc += sx[c] * WT[c * RN + o];
    xdbl[(bk * RN + o) * LL + l0 + lr] = acc;
  }
}

// ---------------- scan pass A: per-chunk local scan (h0=0), emit h_end + sum(delta) ----------------
__global__ __launch_bounds__(192) void k_scan_a(
    const float* __restrict__ xs, const float* __restrict__ xdbl,
    const float* __restrict__ ws, const float* __restrict__ bd,
    const float* __restrict__ dt_bias, const float* __restrict__ A_logs,
    float* __restrict__ hend, float* __restrict__ Ssum) {
  int c = blockIdx.x & 63;
  int bk = blockIdx.x >> 6;
  int k = bk & 3;
  int d = threadIdx.x;
  int t0 = c << 6;
  __shared__ float sdt[384];
  __shared__ float4 sB4[256];   // [64 t][4 groups of 4 n]
  float* sBf = (float*)sB4;
  const float* dtbase = xdbl + (size_t)bk * (RN * LL);
  for (int i = d; i < 384; i += 192) sdt[i] = fsign(dtbase[t0 * 6 + i]);
  {
    const float4* Bp = (const float4*)(xdbl + ((size_t)bk * RN + RR) * LL);
    for (int i = d; i < 256; i += 192) {
      int n = i >> 4, j = i & 15;
      float4 v = Bp[n * 1024 + (t0 >> 2) + j];
      sBf[(4 * j + 0) * 16 + n] = v.x;
      sBf[(4 * j + 1) * 16 + n] = v.y;
      sBf[(4 * j + 2) * 16 + n] = v.z;
      sBf[(4 * j + 3) * 16 + n] = v.w;
    }
  }
  float wd[6];
  {
    const float* wdp = ws + OFF_WDB + (k * DN + d) * RR;
    #pragma unroll
    for (int r = 0; r < RR; ++r) wd[r] = wdp[r];
  }
  float biasd = bd[k * DN + d] + dt_bias[k * DN + d];
  float An[16];
  {
    const float* ap = A_logs + (k * DN + d) * NN;
    #pragma unroll
    for (int n = 0; n < NN; ++n) An[n] = -expf(ap[n]) * LOG2E;
  }
  float h[16];
  #pragma unroll
  for (int n = 0; n < NN; ++n) h[n] = 0.f;
  float S = 0.f;
  const float* up = xs + ((size_t)bk * DN + d) * LL + t0;
  __syncthreads();
  #pragma unroll 1
  for (int tt = 0; tt < 16; ++tt) {
    float4 u4 = *(const float4*)(up + 4 * tt);
    #pragma unroll
    for (int q = 0; q < 4; ++q) {
      int t = 4 * tt + q;
      float uv = (q == 0) ? u4.x : (q == 1) ? u4.y : (q == 2) ? u4.z : u4.w;
      float acc = biasd;
      #pragma unroll
      for (int r = 0; r < RR; ++r) acc += sdt[t * 6 + r] * wd[r];
      float dv = softplusf(acc);
      S += dv;
      float du = dv * uv;
      #pragma unroll
      for (int g = 0; g < 4; ++g) {
        float4 bv = sB4[t * 4 + g];
        float a0 = exp2f(dv * An[4 * g + 0]);
        float a1 = exp2f(dv * An[4 * g + 1]);
        float a2 = exp2f(dv * An[4 * g + 2]);
        float a3 = exp2f(dv * An[4 * g + 3]);
        h[4 * g + 0] = a0 * h[4 * g + 0] + du * bv.x;
        h[4 * g + 1] = a1 * h[4 * g + 1] + du * bv.y;
        h[4 * g + 2] = a2 * h[4 * g + 2] + du * bv.z;
        h[4 * g + 3] = a3 * h[4 * g + 3] + du * bv.w;
      }
    }
  }
  float* hp = hend + (size_t)c * 49152 + (size_t)(bk * DN + d) * 16;
  #pragma unroll
  for (int n = 0; n < NN; n += 4)
    *(float4*)(hp + n) = make_float4(h[n], h[n + 1], h[n + 2], h[n + 3]);
  Ssum[c * 3072 + bk * DN + d] = S;
}

// ---------------- scan pass B: serial combine across 64 chunks ----------------
__global__ __launch_bounds__(256) void k_scan_b(
    const float* __restrict__ A_logs, const float* __restrict__ Ssum,
    float* __restrict__ hend) {
  int tid = blockIdx.x * 256 + threadIdx.x;   // (bk*192+d)*16 + n
  int bkd = tid >> 4, n = tid & 15;
  int bk = bkd / DN, d = bkd - bk * DN;
  int k = bk & 3;
  float An2 = -expf(A_logs[(k * DN + d) * NN + n]) * LOG2E;
  float h = 0.f;
  float Sc = Ssum[bkd];
  float he = hend[tid];
  #pragma unroll 1
  for (int c = 0; c < 64; ++c) {
    float Sn = 0.f, hn = 0.f;
    if (c < 63) {
      Sn = Ssum[(c + 1) * 3072 + bkd];
      hn = hend[(size_t)(c + 1) * 49152 + tid];
    }
    hend[(size_t)c * 49152 + tid] = h;   // h0 entering chunk c
    h = exp2f(An2 * Sc) * h + he;
    Sc = Sn; he = hn;
  }
}

// ---------------- scan pass C: recompute local scan with true h0, emit y ----------------
__global__ __launch_bounds__(192) void k_scan_c(
    const float* __restrict__ xs, const float* __restrict__ xdbl,
    const float* __restrict__ ws, const float* __restrict__ bd,
    const float* __restrict__ dt_bias, const float* __restrict__ A_logs,
    const float* __restrict__ Ds, const float* __restrict__ h0buf,
    float* __restrict__ y) {
  int c = blockIdx.x & 63;
  int bk = blockIdx.x >> 6;
  int k = bk & 3;
  int d = threadIdx.x;
  int t0 = c << 6;
  __shared__ float sdt[384];
  __shared__ float4 sB4[256];
  __shared__ float4 sC4[256];
  float* sBf = (float*)sB4;
  float* sCf = (float*)sC4;
  const float* dtbase = xdbl + (size_t)bk * (RN * LL);
  for (int i = d; i < 384; i += 192) sdt[i] = fsign(dtbase[t0 * 6 + i]);
  {
    const float4* Bp = (const float4*)(xdbl + ((size_t)bk * RN + RR) * LL);
    const float4* Cp = (const float4*)(xdbl + ((size_t)bk * RN + RR + NN) * LL);
    for (int i = d; i < 256; i += 192) {
      int n = i >> 4, j = i & 15;
      float4 v = Bp[n * 1024 + (t0 >> 2) + j];
      sBf[(4 * j + 0) * 16 + n] = v.x;
      sBf[(4 * j + 1) * 16 + n] = v.y;
      sBf[(4 * j + 2) * 16 + n] = v.z;
      sBf[(4 * j + 3) * 16 + n] = v.w;
      float4 w = Cp[n * 1024 + (t0 >> 2) + j];
      sCf[(4 * j + 0) * 16 + n] = w.x;
      sCf[(4 * j + 1) * 16 + n] = w.y;
      sCf[(4 * j + 2) * 16 + n] = w.z;
      sCf[(4 * j + 3) * 16 + n] = w.w;
    }
  }
  float wd[6];
  {
    const float* wdp = ws + OFF_WDB + (k * DN + d) * RR;
    #pragma unroll
    for (int r = 0; r < RR; ++r) wd[r] = wdp[r];
  }
  float biasd = bd[k * DN + d] + dt_bias[k * DN + d];
  float Dd = Ds[k * DN + d];
  float An[16];
  {
    const float* ap = A_logs + (k * DN + d) * NN;
    #pragma unroll
    for (int n = 0; n < NN; ++n) An[n] = -expf(ap[n]) * LOG2E;
  }
  float h[16];
  {
    const float* hp = h0buf + (size_t)c * 49152 + (size_t)(bk * DN + d) * 16;
    #pragma unroll
    for (int n = 0; n < NN; n += 4) {
      float4 v = *(const float4*)(hp + n);
      h[n] = v.x; h[n + 1] = v.y; h[n + 2] = v.z; h[n + 3] = v.w;
    }
  }
  const float* up = xs + ((size_t)bk * DN + d) * LL + t0;
  float* yb = y + (size_t)(bk >> 2) * (LL * DN);
  __syncthreads();
  #pragma unroll 1
  for (int tt = 0; tt < 16; ++tt) {
    float4 u4 = *(const float4*)(up + 4 * tt);
    #pragma unroll
    for (int q = 0; q < 4; ++q) {
      int t = 4 * tt + q;
      float uv = (q == 0) ? u4.x : (q == 1) ? u4.y : (q == 2) ? u4.z : u4.w;
      float acc = biasd;
      #pragma unroll
      for (int r = 0; r < RR; ++r) acc += sdt[t * 6 + r] * wd[r];
      float dv = softplusf(acc);
      float du = dv * uv;
      float yv = Dd * uv;
      #pragma unroll
      for (int g = 0; g < 4; ++g) {
        float4 bv = sB4[t * 4 + g];
        float4 cv = sC4[t * 4 + g];
        float a0 = exp2f(dv * An[4 * g + 0]);
        float a1 = exp2f(dv * An[4 * g + 1]);
        float a2 = exp2f(dv * An[4 * g + 2]);
        float a3 = exp2f(dv * An[4 * g + 3]);
        h[4 * g + 0] = a0 * h[4 * g + 0] + du * bv.x;
        h[4 * g + 1] = a1 * h[4 * g + 1] + du * bv.y;
        h[4 * g + 2] = a2 * h[4 * g + 2] + du * bv.z;
        h[4 * g + 3] = a3 * h[4 * g + 3] + du * bv.w;
        yv += cv.x * h[4 * g + 0];
        yv += cv.y * h[4 * g + 1];
        yv += cv.z * h[4 * g + 2];
        yv += cv.w * h[4 * g + 3];
      }
      int ta = t0 + t, l;
      if (k == 0)      l = ta;
      else if (k == 1) l = ((ta & 63) << 6) | (ta >> 6);
      else if (k == 2) l = 4095 - ta;
      else { int t2 = 4095 - ta; l = ((t2 & 63) << 6) | (t2 >> 6); }
      atomicAdd(&yb[(size_t)l * DN + d], yv);
    }
  }
}

// ---------------- LayerNorm over Dn + * silu(z) + sign; y layout [b][L][d] ----------------
__global__ __launch_bounds__(256) void k_ln(
    const float* __restrict__ y, const float* __restrict__ zs,
    const float* __restrict__ ln_w, const float* __restrict__ ln_b,
    float* __restrict__ ybuf) {
  __shared__ float ty[64 * 193];
  __shared__ float ps[256];
  __shared__ float smu[64], srs[64];
  int b = blockIdx.x >> 6;
  int l0 = (blockIdx.x & 63) << 6;
  const float* yp = y + (size_t)(b * LL + l0) * DN;
  {
    int lc = threadIdx.x / DN, d2 = threadIdx.x - lc * DN;
    for (int i = threadIdx.x; i < 64 * DN; i += 256) {
      ty[lc * 193 + d2] = yp[i];
      d2 += 256;
      if (d2 >= DN) { d2 -= DN; lc += 1; if (d2 >= DN) { d2 -= DN; lc += 1; } }
    }
  }
  __syncthreads();
  int lc = threadIdx.x & 63, part = threadIdx.x >> 6;
  float s = 0.f;
  for (int d = part * 48; d < part * 48 + 48; ++d) s += ty[lc * 193 + d];
  ps[threadIdx.x] = s;
  __syncthreads();
  if (threadIdx.x < 64)
    smu[threadIdx.x] = (ps[threadIdx.x] + ps[threadIdx.x + 64] +
                        ps[threadIdx.x + 128] + ps[threadIdx.x + 192]) / (float)DN;
  __syncthreads();
  float mu = smu[lc];
  float q = 0.f;
  for (int d = part * 48; d < part * 48 + 48; ++d) {
    float v = ty[lc * 193 + d] - mu; q += v * v;
  }
  ps[threadIdx.x] = q;
  __syncthreads();
  if (threadIdx.x < 64) {
    float var = (ps[threadIdx.x] + ps[threadIdx.x + 64] +
                 ps[threadIdx.x + 128] + ps[threadIdx.x + 192]) / (float)DN;
    srs[threadIdx.x] = rsqrtf(var + 1e-5f);
  }
  __syncthreads();
  {
    int lc2 = threadIdx.x / DN, d2 = threadIdx.x - lc2 * DN;
    const float* zp = zs + (size_t)(b * LL + l0) * DN;
    float* op = ybuf + (size_t)(b * LL + l0) * DN;
    for (int i = threadIdx.x; i < 64 * DN; i += 256) {
      float v = ty[lc2 * 193 + d2];
      float ln = (v - smu[lc2]) * srs[lc2] * ln_w[d2] + ln_b[d2];
      op[i] = fsign(ln * zp[i]);
      d2 += 256;
      if (d2 >= DN) { d2 -= DN; lc2 += 1; if (d2 >= DN) { d2 -= DN; lc2 += 1; } }
    }
  }
}

// ---------------- output bilinear ----------------
__global__ __launch_bounds__(256) void k_out(
    const float* __restrict__ ybuf, const float* __restrict__ ws,
    const float* __restrict__ b_out, float* __restrict__ out) {
  __shared__ float ssy[16 * DN];
  int p0 = blockIdx.x * 16;
  for (int i = threadIdx.x; i < 16 * DN; i += 256) ssy[i] = ybuf[p0 * DN + i];
  __syncthreads();
  const float* WT = ws + OFF_WOUT_T;
  for (int oi = threadIdx.x; oi < 16 * DM; oi += 256) {
    int pr = oi / DM, m = oi % DM;
    float acc = b_out[m];
    const float* sy = ssy + pr * DN;
    for (int c = 0; c < DN; ++c) acc += sy[c] * WT[c * DM + m];
    out[(p0 + pr) * DM + m] = acc;
  }
}

extern "C" void kernel_launch(void* const* d_in, const int* in_sizes, int n_in,
                              void* d_out, int out_size, void* d_ws, size_t ws_size,
                              hipStream_t stream) {
  const float* x       = (const float*)d_in[0];
  const float* W_in    = (const float*)d_in[1];
  const float* b_in    = (const float*)d_in[2];
  const float* s_in    = (const float*)d_in[3];
  const float* move0_b = (const float*)d_in[4];
  const float* conv_W  = (const float*)d_in[5];
  const float* conv_b  = (const float*)d_in[6];
  const float* rp_b0   = (const float*)d_in[7];
  const float* prelu_a = (const float*)d_in[8];
  const float* rp_b1   = (const float*)d_in[9];
  const float* Wl      = (const float*)d_in[10];
  const float* bl      = (const float*)d_in[11];
  const float* sl      = (const float*)d_in[12];
  const float* Wd      = (const float*)d_in[13];
  const float* bd      = (const float*)d_in[14];
  const float* sd      = (const float*)d_in[15];
  const float* dt_bias = (const float*)d_in[16];
  const float* A_logs  = (const float*)d_in[17];
  const float* Ds      = (const float*)d_in[18];
  const float* ln_w    = (const float*)d_in[19];
  const float* ln_b    = (const float*)d_in[20];
  const float* W_out   = (const float*)d_in[21];
  const float* b_out   = (const float*)d_in[22];
  const float* s_out   = (const float*)d_in[23];
  float* ws  = (float*)d_ws;
  float* out = (float*)d_out;

  hipLaunchKernelGGL(k_prep, dim3(1592), dim3(64), 0, stream,
                     W_in, s_in, W_out, s_out, Wl, sl, Wd, sd, conv_W, ws);
  hipLaunchKernelGGL(k_bilin_in, dim3(2048), dim3(384), 0, stream,
                     x, b_in, ws, ws + OFF_XC, ws + OFF_ZS);
  hipLaunchKernelGGL(k_sign, dim3(12288), dim3(256), 0, stream,
                     ws + OFF_XC, move0_b, ws + OFF_XSG);
  hipLaunchKernelGGL(k_conv, dim3(768), dim3(256), 0, stream,
                     ws + OFF_XSG, ws + OFF_XC, ws, conv_b, rp_b0, prelu_a, rp_b1,
                     ws + OFF_XCONV);
  hipLaunchKernelGGL(k_build_xs, dim3(49152), dim3(256), 0, stream,
                     ws + OFF_XCONV, ws + OFF_XS);
  hipLaunchKernelGGL(k_xdbl, dim3(2048), dim3(256), 0, stream,
                     ws + OFF_XS, ws, bl, ws + OFF_XDBL);
  // chunked parallel scan
  hipLaunchKernelGGL(k_scan_a, dim3(1024), dim3(192), 0, stream,
                     ws + OFF_XS, ws + OFF_XDBL, ws, bd, dt_bias, A_logs,
                     ws + OFF_HEND, ws + OFF_SSUM);
  hipLaunchKernelGGL(k_scan_b, dim3(192), dim3(256), 0, stream,
                     A_logs, ws + OFF_SSUM, ws + OFF_HEND);
  hipMemsetAsync((void*)(ws + OFF_XC), 0, (size_t)3145728 * sizeof(float), stream);
  hipLaunchKernelGGL(k_scan_c, dim3(1024), dim3(192), 0, stream,
                     ws + OFF_XS, ws + OFF_XDBL, ws, bd, dt_bias, A_logs, Ds,
                     ws + OFF_HEND, ws + OFF_XC);
  hipLaunchKernelGGL(k_ln, dim3(256), dim3(256), 0, stream,
                     ws + OFF_XC, ws + OFF_ZS, ln_w, ln_b, ws + OFF_XCONV);
  hipLaunchKernelGGL(k_out, dim3(1024), dim3(256), 0, stream,
                     ws + OFF_XCONV, ws, b_out, out);
}

// Round 3
// 619.309 us; speedup vs baseline: 3.3235x; 1.4398x over previous
//
#include <hip/hip_runtime.h>
#include <math.h>
#include <stdint.h>

// Problem constants
#define BB 4
#define HH 64
#define WW2 64
#define DM 96
#define DN 192
#define KK 4
#define NN 16
#define RR 6
#define LL 4096
#define RN 38   // R + 2N

#define LOG2E 1.4426950408889634f
#define LN2   0.6931471805599453f

// Workspace layout (float offsets). Peak = 24,931,328 floats = 99.7 MB.
#define OFF_WBT_IN   0           // 96*384   transposed in-proj sign weights
#define OFF_WOUT_T   36864       // 192*96   transposed out-proj sign weights
#define OFF_WLB_T    55296       // 4*192*38 transposed x_dbl sign weights
#define OFF_WDB      84480       // 768*6    dts sign weights
#define OFF_WCS      89088       // packed conv weights u32[192][56]; region reused as Ssum by scan
#define OFF_WAUX     99840       // int[192][8]: csL,csR,rsT,rsB,wsTL,wsTR,wsBL,wsBR
#define OFF_WSC      101376      // float[192] conv scale
#define OFF_XB       102400      // u32[4][6][66*66] zero-padded sign bit-planes (104544 words)
#define OFF_XC       420864      // 3145728  xp transposed (B,Dn,L); reused as y accumulator [b][L][d]
#define OFF_ZS       3566592     // 3145728  silu(z) in (B,L,Dn)
#define OFF_XCONV    6712320     // 3145728  conv out (B,Dn,L); reused as hend/h0; then ybuf
#define OFF_XS       9858048     // 12582912 4-direction scan input
#define OFF_XDBL     22440960    // 4*4*38*4096 x_dbl in (B,K,38,L)
#define OFF_HEND     OFF_XCONV
#define OFF_SSUM     OFF_WCS

#define PLANE 4356   // 66*66

__device__ __forceinline__ float fsign(float v) {
  return (v > 0.f) ? 1.f : ((v < 0.f) ? -1.f : 0.f);
}
__device__ __forceinline__ float softplusf(float v) {
  return fmaxf(v, 0.f) + LN2 * log2f(1.f + exp2f(-fabsf(v) * LOG2E));
}
__device__ __forceinline__ float siluf(float v) {
  return v / (1.f + expf(-v));
}
__device__ __forceinline__ float waveAllSum(float s) {
  #pragma unroll
  for (int off = 32; off; off >>= 1) s += __shfl_xor(s, off, 64);
  return s;
}

// ---------------- prep: all sign-weight transforms + conv bit-pack ----------------
__global__ __launch_bounds__(64) void k_prep(
    const float* __restrict__ W_in, const float* __restrict__ s_in,
    const float* __restrict__ W_out, const float* __restrict__ s_out,
    const float* __restrict__ Wl, const float* __restrict__ sl,
    const float* __restrict__ Wd, const float* __restrict__ sd,
    const float* __restrict__ convW, float* __restrict__ ws) {
  int r = blockIdx.x, lane = threadIdx.x;
  if (r < 384) {
    const float* row = W_in + r * DM;
    float s = 0.f;
    for (int c = lane; c < DM; c += 64) s += row[c];
    s = waveAllSum(s);
    float mean = s / (float)DM, sc = s_in[r];
    float* WT = ws + OFF_WBT_IN;
    for (int c = lane; c < DM; c += 64) WT[c * 384 + r] = sc * fsign(row[c] - mean);
  } else if (r < 480) {
    int m = r - 384;
    const float* row = W_out + m * DN;
    float s = 0.f;
    for (int c = lane; c < DN; c += 64) s += row[c];
    s = waveAllSum(s);
    float mean = s / (float)DN, sc = s_out[m];
    float* WT = ws + OFF_WOUT_T;
    for (int c = lane; c < DN; c += 64) WT[c * DM + m] = sc * fsign(row[c] - mean);
  } else if (r < 632) {
    int idx = r - 480;
    const float* row = Wl + idx * DN;
    float s = 0.f;
    for (int c = lane; c < DN; c += 64) s += row[c];
    s = waveAllSum(s);
    float mean = s / (float)DN, sc = sl[idx];
    int k = idx / RN, o = idx % RN;
    float* WT = ws + OFF_WLB_T + k * (DN * RN);
    for (int c = lane; c < DN; c += 64) WT[c * RN + o] = sc * fsign(row[c] - mean);
  } else if (r < 1400) {
    int idx = r - 632;
    const float* row = Wd + idx * RR;
    float s = (lane < RR) ? row[lane] : 0.f;
    s = waveAllSum(s);
    float mean = s / (float)RR, sc = sd[idx];
    if (lane < RR) (ws + OFF_WDB)[idx * RR + lane] = sc * fsign(row[lane] - mean);
  } else {
    // conv channel o: sc, packed bits, tap-sum aux
    int o = r - 1400;
    const float* row = convW + o * 1728;
    float s = 0.f;
    for (int j = lane; j < 1728; j += 64) s += fabsf(row[j]);
    s = waveAllSum(s);
    float sc = s / 1728.f;
    uint32_t* wb = (uint32_t*)(ws + OFF_WCS);
    int* aux = (int*)(ws + OFF_WAUX);
    float* scf = ws + OFF_WSC;
    uint32_t word = 0;
    if (lane < 54) {
      int cw = lane / 9, tap = lane % 9;
      #pragma unroll
      for (int i = 0; i < 32; ++i)
        word |= (row[(cw * 32 + i) * 9 + tap] > 0.f ? 1u : 0u) << i;
      wb[o * 56 + lane] = word;
    } else if (lane < 56) {
      wb[o * 56 + lane] = 0u;
    }
    int pc = (lane < 54) ? 2 * (int)__popc(word) - 32 : 0;
    int tapid = lane % 9;
    int wst = 0;
    #pragma unroll
    for (int cw = 0; cw < 6; ++cw) wst += __shfl(pc, cw * 9 + tapid, 64);
    int w_t[9];
    #pragma unroll
    for (int t9 = 0; t9 < 9; ++t9) w_t[t9] = __shfl(wst, t9, 64);
    if (lane == 0) {
      aux[o * 8 + 0] = w_t[0] + w_t[3] + w_t[6];   // csL (kx=0 col)
      aux[o * 8 + 1] = w_t[2] + w_t[5] + w_t[8];   // csR (kx=2 col)
      aux[o * 8 + 2] = w_t[0] + w_t[1] + w_t[2];   // rsT (ky=0 row)
      aux[o * 8 + 3] = w_t[6] + w_t[7] + w_t[8];   // rsB (ky=2 row)
      aux[o * 8 + 4] = w_t[0];                     // TL corner
      aux[o * 8 + 5] = w_t[2];                     // TR
      aux[o * 8 + 6] = w_t[6];                     // BL
      aux[o * 8 + 7] = w_t[8];                     // BR
      scf[o] = sc;
    }
  }
}

// ---------------- input bilinear: xz = sign(x) @ WbT + b ----------------
__global__ __launch_bounds__(384) void k_bilin_in(
    const float* __restrict__ x, const float* __restrict__ b_in,
    const float* __restrict__ ws, float* __restrict__ xc, float* __restrict__ zs) {
  __shared__ float sx[8 * DM];
  int p0 = blockIdx.x * 8;
  for (int i = threadIdx.x; i < 8 * DM; i += 384) sx[i] = fsign(x[p0 * DM + i]);
  __syncthreads();
  int o = threadIdx.x;
  const float* WT = ws + OFF_WBT_IN;
  float acc[8];
  float bias = b_in[o];
  #pragma unroll
  for (int i = 0; i < 8; ++i) acc[i] = bias;
  for (int c = 0; c < DM; ++c) {
    float w = WT[c * 384 + o];
    #pragma unroll
    for (int i = 0; i < 8; ++i) acc[i] += w * sx[i * DM + c];
  }
  int b = p0 >> 12, l0 = p0 & 4095;
  if (o < DN) {
    #pragma unroll
    for (int i = 0; i < 8; ++i) xc[(b * DN + o) * LL + l0 + i] = acc[i];
  } else {
    int oz = o - DN;
    #pragma unroll
    for (int i = 0; i < 8; ++i) zs[(p0 + i) * DN + oz] = siluf(acc[i]);
  }
}

// ---------------- pack sign(xc+move0) into zero-padded bit-planes ----------------
// thread = (b, cw, h, w2): 2 consecutive pixels, 32 channels
__global__ __launch_bounds__(256) void k_pack(
    const float* __restrict__ xc, const float* __restrict__ move0,
    uint32_t* __restrict__ xb) {
  int t = blockIdx.x * 256 + threadIdx.x;
  int w2 = t & 31;
  int h = (t >> 5) & 63;
  int g = t >> 11;          // 0..23
  int cw = g % 6, b = g / 6;
  const float* xp = xc + ((size_t)(b * DN + cw * 32)) * LL + h * 64 + w2 * 2;
  uint32_t w0 = 0, w1 = 0;
  #pragma unroll
  for (int i = 0; i < 32; ++i) {
    float m = move0[cw * 32 + i];
    float2 v = *(const float2*)(xp + (size_t)i * LL);
    w0 |= (v.x + m > 0.f ? 1u : 0u) << i;
    w1 |= (v.y + m > 0.f ? 1u : 0u) << i;
  }
  uint32_t* plane = xb + (size_t)(b * 6 + cw) * PLANE;
  plane[(h + 1) * 66 + 1 + w2 * 2] = w0;
  plane[(h + 1) * 66 + 2 + w2 * 2] = w1;
}

// ---------------- XNOR-popcount binary 3x3 conv + RPReLU + residual + SiLU ----------------
// grid = og(4) x stripe(16) x b(4); block = 64w x 4rows; each thread: 48 output channels
__global__ __launch_bounds__(256) void k_conv(
    const uint32_t* __restrict__ xb, const float* __restrict__ xc,
    const uint32_t* __restrict__ wbits, const int* __restrict__ aux,
    const float* __restrict__ scf, const float* __restrict__ conv_b,
    const float* __restrict__ rp_b0, const float* __restrict__ prelu_a,
    const float* __restrict__ rp_b1, float* __restrict__ xconv) {
  int og = blockIdx.x & 3;
  int stripe = (blockIdx.x >> 2) & 15;
  int b = blockIdx.x >> 6;
  int w = threadIdx.x & 63, r = threadIdx.x >> 6;
  int h = stripe * 4 + r;

  __shared__ uint32_t swb[48 * 56];
  __shared__ int saux[48 * 8];
  __shared__ float sconst[48 * 4];
  for (int i = threadIdx.x; i < 48 * 56; i += 256) swb[i] = wbits[og * (48 * 56) + i];
  for (int i = threadIdx.x; i < 48 * 8; i += 256) saux[i] = aux[og * (48 * 8) + i];
  if (threadIdx.x < 48) {
    int o = og * 48 + threadIdx.x;
    sconst[threadIdx.x * 4 + 0] = scf[o];
    sconst[threadIdx.x * 4 + 1] = conv_b[o] + rp_b0[o];
    sconst[threadIdx.x * 4 + 2] = prelu_a[o];
    sconst[threadIdx.x * 4 + 3] = rp_b1[o];
  }

  // load 54 x-words for this pixel
  uint32_t xw[6][9];
  const uint32_t* xpb = xb + (size_t)b * 6 * PLANE;
  #pragma unroll
  for (int cw = 0; cw < 6; ++cw) {
    const uint32_t* plane = xpb + cw * PLANE + (h + 1) * 66 + (w + 1);
    #pragma unroll
    for (int dy = 0; dy < 3; ++dy) {
      #pragma unroll
      for (int dx = 0; dx < 3; ++dx)
        xw[cw][dy * 3 + dx] = plane[(dy - 1) * 66 + (dx - 1)];
    }
  }
  bool isL = (w == 0), isR = (w == 63);
  bool isT = (h == 0), isB = (h == 63);   // wave-uniform
  const float* xcp = xc + ((size_t)(b * DN + og * 48)) * LL + h * 64 + w;
  float* xop = xconv + ((size_t)(b * DN + og * 48)) * LL + h * 64 + w;
  __syncthreads();

  #pragma unroll 1
  for (int oc = 0; oc < 48; ++oc) {
    const uint32_t* wp = &swb[oc * 56];
    int P = 0;
    #pragma unroll
    for (int cw = 0; cw < 6; ++cw) {
      int pp = 0;
      #pragma unroll
      for (int t = 0; t < 9; ++t) pp += (int)__popc(wp[cw * 9 + t] ^ xw[cw][t]);
      P += pp;
    }
    int corr = isL ? saux[oc * 8 + 0] : (isR ? saux[oc * 8 + 1] : 0);
    if (isT) {
      corr += saux[oc * 8 + 2];
      if (isL) corr -= saux[oc * 8 + 4];
      if (isR) corr -= saux[oc * 8 + 5];
    }
    if (isB) {
      corr += saux[oc * 8 + 3];
      if (isL) corr -= saux[oc * 8 + 6];
      if (isR) corr -= saux[oc * 8 + 7];
    }
    float acc = sconst[oc * 4 + 0] * (float)(1728 - 2 * P + corr);
    float t = acc + sconst[oc * 4 + 1];
    t = (t >= 0.f) ? t : sconst[oc * 4 + 2] * t;
    t += sconst[oc * 4 + 3] + *xcp;
    *xop = siluf(t);
    xcp += LL; xop += LL;
  }
}

// ---------------- build 4-direction scan input xs ----------------
__global__ __launch_bounds__(256) void k_build_xs(const float* __restrict__ xconv,
                                                  float* __restrict__ xs) {
  int idx = blockIdx.x * 256 + threadIdx.x;
  int l = idx & 4095;
  int d = (idx >> 12) % DN;
  int k = ((idx >> 12) / DN) % KK;
  int b = idx / (KK * DN * LL);
  int src;
  if (k == 0)      src = l;
  else if (k == 1) src = ((l & 63) << 6) | (l >> 6);
  else if (k == 2) src = 4095 - l;
  else { int t2 = 4095 - l; src = ((t2 & 63) << 6) | (t2 >> 6); }
  xs[idx] = xconv[(b * DN + d) * LL + src];
}

// ---------------- x_dbl bilinear ----------------
__global__ __launch_bounds__(256) void k_xdbl(
    const float* __restrict__ xs, const float* __restrict__ ws,
    const float* __restrict__ bl, float* __restrict__ xdbl) {
  __shared__ float ssx[32 * DN];
  int bk = blockIdx.x >> 7;
  int l0 = (blockIdx.x & 127) << 5;
  int k = bk & 3;
  const float* base = xs + (size_t)bk * (DN * LL) + (size_t)l0 * DN;
  for (int i = threadIdx.x; i < 32 * DN; i += 256) ssx[i] = fsign(base[i]);
  __syncthreads();
  const float* WT = ws + OFF_WLB_T + k * (DN * RN);
  for (int oi = threadIdx.x; oi < 32 * RN; oi += 256) {
    int lr = oi / RN, o = oi % RN;
    float acc = bl[k * RN + o];
    const float* sx = ssx + lr * DN;
    for (int c = 0; c < DN; ++c) acc += sx[c] * WT[c * RN + o];
    xdbl[(bk * RN + o) * LL + l0 + lr] = acc;
  }
}

// ---------------- scan pass A ----------------
__global__ __launch_bounds__(192) void k_scan_a(
    const float* __restrict__ xs, const float* __restrict__ xdbl,
    const float* __restrict__ ws, const float* __restrict__ bd,
    const float* __restrict__ dt_bias, const float* __restrict__ A_logs,
    float* __restrict__ hend, float* __restrict__ Ssum) {
  int c = blockIdx.x & 63;
  int bk = blockIdx.x >> 6;
  int k = bk & 3;
  int d = threadIdx.x;
  int t0 = c << 6;
  __shared__ float sdt[384];
  __shared__ float4 sB4[256];
  float* sBf = (float*)sB4;
  const float* dtbase = xdbl + (size_t)bk * (RN * LL);
  for (int i = d; i < 384; i += 192) sdt[i] = fsign(dtbase[t0 * 6 + i]);
  {
    const float4* Bp = (const float4*)(xdbl + ((size_t)bk * RN + RR) * LL);
    for (int i = d; i < 256; i += 192) {
      int n = i >> 4, j = i & 15;
      float4 v = Bp[n * 1024 + (t0 >> 2) + j];
      sBf[(4 * j + 0) * 16 + n] = v.x;
      sBf[(4 * j + 1) * 16 + n] = v.y;
      sBf[(4 * j + 2) * 16 + n] = v.z;
      sBf[(4 * j + 3) * 16 + n] = v.w;
    }
  }
  float wd[6];
  {
    const float* wdp = ws + OFF_WDB + (k * DN + d) * RR;
    #pragma unroll
    for (int r = 0; r < RR; ++r) wd[r] = wdp[r];
  }
  float biasd = bd[k * DN + d] + dt_bias[k * DN + d];
  float An[16];
  {
    const float* ap = A_logs + (k * DN + d) * NN;
    #pragma unroll
    for (int n = 0; n < NN; ++n) An[n] = -expf(ap[n]) * LOG2E;
  }
  float h[16];
  #pragma unroll
  for (int n = 0; n < NN; ++n) h[n] = 0.f;
  float S = 0.f;
  const float* up = xs + ((size_t)bk * DN + d) * LL + t0;
  __syncthreads();
  #pragma unroll 1
  for (int tt = 0; tt < 16; ++tt) {
    float4 u4 = *(const float4*)(up + 4 * tt);
    #pragma unroll
    for (int q = 0; q < 4; ++q) {
      int t = 4 * tt + q;
      float uv = (q == 0) ? u4.x : (q == 1) ? u4.y : (q == 2) ? u4.z : u4.w;
      float acc = biasd;
      #pragma unroll
      for (int r = 0; r < RR; ++r) acc += sdt[t * 6 + r] * wd[r];
      float dv = softplusf(acc);
      S += dv;
      float du = dv * uv;
      #pragma unroll
      for (int g = 0; g < 4; ++g) {
        float4 bv = sB4[t * 4 + g];
        float a0 = exp2f(dv * An[4 * g + 0]);
        float a1 = exp2f(dv * An[4 * g + 1]);
        float a2 = exp2f(dv * An[4 * g + 2]);
        float a3 = exp2f(dv * An[4 * g + 3]);
        h[4 * g + 0] = a0 * h[4 * g + 0] + du * bv.x;
        h[4 * g + 1] = a1 * h[4 * g + 1] + du * bv.y;
        h[4 * g + 2] = a2 * h[4 * g + 2] + du * bv.z;
        h[4 * g + 3] = a3 * h[4 * g + 3] + du * bv.w;
      }
    }
  }
  float* hp = hend + (size_t)c * 49152 + (size_t)(bk * DN + d) * 16;
  #pragma unroll
  for (int n = 0; n < NN; n += 4)
    *(float4*)(hp + n) = make_float4(h[n], h[n + 1], h[n + 2], h[n + 3]);
  Ssum[c * 3072 + bk * DN + d] = S;
}

// ---------------- scan pass B ----------------
__global__ __launch_bounds__(256) void k_scan_b(
    const float* __restrict__ A_logs, const float* __restrict__ Ssum,
    float* __restrict__ hend) {
  int tid = blockIdx.x * 256 + threadIdx.x;
  int bkd = tid >> 4, n = tid & 15;
  int bk = bkd / DN, d = bkd - bk * DN;
  int k = bk & 3;
  float An2 = -expf(A_logs[(k * DN + d) * NN + n]) * LOG2E;
  float h = 0.f;
  float Sc = Ssum[bkd];
  float he = hend[tid];
  #pragma unroll 1
  for (int c = 0; c < 64; ++c) {
    float Sn = 0.f, hn = 0.f;
    if (c < 63) {
      Sn = Ssum[(c + 1) * 3072 + bkd];
      hn = hend[(size_t)(c + 1) * 49152 + tid];
    }
    hend[(size_t)c * 49152 + tid] = h;
    h = exp2f(An2 * Sc) * h + he;
    Sc = Sn; he = hn;
  }
}

// ---------------- scan pass C ----------------
__global__ __launch_bounds__(192) void k_scan_c(
    const float* __restrict__ xs, const float* __restrict__ xdbl,
    const float* __restrict__ ws, const float* __restrict__ bd,
    const float* __restrict__ dt_bias, const float* __restrict__ A_logs,
    const float* __restrict__ Ds, const float* __restrict__ h0buf,
    float* __restrict__ y) {
  int c = blockIdx.x & 63;
  int bk = blockIdx.x >> 6;
  int k = bk & 3;
  int d = threadIdx.x;
  int t0 = c << 6;
  __shared__ float sdt[384];
  __shared__ float4 sB4[256];
  __shared__ float4 sC4[256];
  float* sBf = (float*)sB4;
  float* sCf = (float*)sC4;
  const float* dtbase = xdbl + (size_t)bk * (RN * LL);
  for (int i = d; i < 384; i += 192) sdt[i] = fsign(dtbase[t0 * 6 + i]);
  {
    const float4* Bp = (const float4*)(xdbl + ((size_t)bk * RN + RR) * LL);
    const float4* Cp = (const float4*)(xdbl + ((size_t)bk * RN + RR + NN) * LL);
    for (int i = d; i < 256; i += 192) {
      int n = i >> 4, j = i & 15;
      float4 v = Bp[n * 1024 + (t0 >> 2) + j];
      sBf[(4 * j + 0) * 16 + n] = v.x;
      sBf[(4 * j + 1) * 16 + n] = v.y;
      sBf[(4 * j + 2) * 16 + n] = v.z;
      sBf[(4 * j + 3) * 16 + n] = v.w;
      float4 w = Cp[n * 1024 + (t0 >> 2) + j];
      sCf[(4 * j + 0) * 16 + n] = w.x;
      sCf[(4 * j + 1) * 16 + n] = w.y;
      sCf[(4 * j + 2) * 16 + n] = w.z;
      sCf[(4 * j + 3) * 16 + n] = w.w;
    }
  }
  float wd[6];
  {
    const float* wdp = ws + OFF_WDB + (k * DN + d) * RR;
    #pragma unroll
    for (int r = 0; r < RR; ++r) wd[r] = wdp[r];
  }
  float biasd = bd[k * DN + d] + dt_bias[k * DN + d];
  float Dd = Ds[k * DN + d];
  float An[16];
  {
    const float* ap = A_logs + (k * DN + d) * NN;
    #pragma unroll
    for (int n = 0; n < NN; ++n) An[n] = -expf(ap[n]) * LOG2E;
  }
  float h[16];
  {
    const float* hp = h0buf + (size_t)c * 49152 + (size_t)(bk * DN + d) * 16;
    #pragma unroll
    for (int n = 0; n < NN; n += 4) {
      float4 v = *(const float4*)(hp + n);
      h[n] = v.x; h[n + 1] = v.y; h[n + 2] = v.z; h[n + 3] = v.w;
    }
  }
  const float* up = xs + ((size_t)bk * DN + d) * LL + t0;
  float* yb = y + (size_t)(bk >> 2) * (LL * DN);
  __syncthreads();
  #pragma unroll 1
  for (int tt = 0; tt < 16; ++tt) {
    float4 u4 = *(const float4*)(up + 4 * tt);
    #pragma unroll
    for (int q = 0; q < 4; ++q) {
      int t = 4 * tt + q;
      float uv = (q == 0) ? u4.x : (q == 1) ? u4.y : (q == 2) ? u4.z : u4.w;
      float acc = biasd;
      #pragma unroll
      for (int r = 0; r < RR; ++r) acc += sdt[t * 6 + r] * wd[r];
      float dv = softplusf(acc);
      float du = dv * uv;
      float yv = Dd * uv;
      #pragma unroll
      for (int g = 0; g < 4; ++g) {
        float4 bv = sB4[t * 4 + g];
        float4 cv = sC4[t * 4 + g];
        float a0 = exp2f(dv * An[4 * g + 0]);
        float a1 = exp2f(dv * An[4 * g + 1]);
        float a2 = exp2f(dv * An[4 * g + 2]);
        float a3 = exp2f(dv * An[4 * g + 3]);
        h[4 * g + 0] = a0 * h[4 * g + 0] + du * bv.x;
        h[4 * g + 1] = a1 * h[4 * g + 1] + du * bv.y;
        h[4 * g + 2] = a2 * h[4 * g + 2] + du * bv.z;
        h[4 * g + 3] = a3 * h[4 * g + 3] + du * bv.w;
        yv += cv.x * h[4 * g + 0];
        yv += cv.y * h[4 * g + 1];
        yv += cv.z * h[4 * g + 2];
        yv += cv.w * h[4 * g + 3];
      }
      int ta = t0 + t, l;
      if (k == 0)      l = ta;
      else if (k == 1) l = ((ta & 63) << 6) | (ta >> 6);
      else if (k == 2) l = 4095 - ta;
      else { int t2 = 4095 - ta; l = ((t2 & 63) << 6) | (t2 >> 6); }
      atomicAdd(&yb[(size_t)l * DN + d], yv);
    }
  }
}

// ---------------- LayerNorm over Dn + * silu(z) + sign ----------------
__global__ __launch_bounds__(256) void k_ln(
    const float* __restrict__ y, const float* __restrict__ zs,
    const float* __restrict__ ln_w, const float* __restrict__ ln_b,
    float* __restrict__ ybuf) {
  __shared__ float ty[64 * 193];
  __shared__ float ps[256];
  __shared__ float smu[64], srs[64];
  int b = blockIdx.x >> 6;
  int l0 = (blockIdx.x & 63) << 6;
  const float* yp = y + (size_t)(b * LL + l0) * DN;
  {
    int lc = threadIdx.x / DN, d2 = threadIdx.x - lc * DN;
    for (int i = threadIdx.x; i < 64 * DN; i += 256) {
      ty[lc * 193 + d2] = yp[i];
      d2 += 256;
      if (d2 >= DN) { d2 -= DN; lc += 1; if (d2 >= DN) { d2 -= DN; lc += 1; } }
    }
  }
  __syncthreads();
  int lc = threadIdx.x & 63, part = threadIdx.x >> 6;
  float s = 0.f;
  for (int d = part * 48; d < part * 48 + 48; ++d) s += ty[lc * 193 + d];
  ps[threadIdx.x] = s;
  __syncthreads();
  if (threadIdx.x < 64)
    smu[threadIdx.x] = (ps[threadIdx.x] + ps[threadIdx.x + 64] +
                        ps[threadIdx.x + 128] + ps[threadIdx.x + 192]) / (float)DN;
  __syncthreads();
  float mu = smu[lc];
  float q = 0.f;
  for (int d = part * 48; d < part * 48 + 48; ++d) {
    float v = ty[lc * 193 + d] - mu; q += v * v;
  }
  ps[threadIdx.x] = q;
  __syncthreads();
  if (threadIdx.x < 64) {
    float var = (ps[threadIdx.x] + ps[threadIdx.x + 64] +
                 ps[threadIdx.x + 128] + ps[threadIdx.x + 192]) / (float)DN;
    srs[threadIdx.x] = rsqrtf(var + 1e-5f);
  }
  __syncthreads();
  {
    int lc2 = threadIdx.x / DN, d2 = threadIdx.x - lc2 * DN;
    const float* zp = zs + (size_t)(b * LL + l0) * DN;
    float* op = ybuf + (size_t)(b * LL + l0) * DN;
    for (int i = threadIdx.x; i < 64 * DN; i += 256) {
      float v = ty[lc2 * 193 + d2];
      float ln = (v - smu[lc2]) * srs[lc2] * ln_w[d2] + ln_b[d2];
      op[i] = fsign(ln * zp[i]);
      d2 += 256;
      if (d2 >= DN) { d2 -= DN; lc2 += 1; if (d2 >= DN) { d2 -= DN; lc2 += 1; } }
    }
  }
}

// ---------------- output bilinear ----------------
__global__ __launch_bounds__(256) void k_out(
    const float* __restrict__ ybuf, const float* __restrict__ ws,
    const float* __restrict__ b_out, float* __restrict__ out) {
  __shared__ float ssy[16 * DN];
  int p0 = blockIdx.x * 16;
  for (int i = threadIdx.x; i < 16 * DN; i += 256) ssy[i] = ybuf[p0 * DN + i];
  __syncthreads();
  const float* WT = ws + OFF_WOUT_T;
  for (int oi = threadIdx.x; oi < 16 * DM; oi += 256) {
    int pr = oi / DM, m = oi % DM;
    float acc = b_out[m];
    const float* sy = ssy + pr * DN;
    for (int c = 0; c < DN; ++c) acc += sy[c] * WT[c * DM + m];
    out[(p0 + pr) * DM + m] = acc;
  }
}

extern "C" void kernel_launch(void* const* d_in, const int* in_sizes, int n_in,
                              void* d_out, int out_size, void* d_ws, size_t ws_size,
                              hipStream_t stream) {
  const float* x       = (const float*)d_in[0];
  const float* W_in    = (const float*)d_in[1];
  const float* b_in    = (const float*)d_in[2];
  const float* s_in    = (const float*)d_in[3];
  const float* move0_b = (const float*)d_in[4];
  const float* conv_W  = (const float*)d_in[5];
  const float* conv_b  = (const float*)d_in[6];
  const float* rp_b0   = (const float*)d_in[7];
  const float* prelu_a = (const float*)d_in[8];
  const float* rp_b1   = (const float*)d_in[9];
  const float* Wl      = (const float*)d_in[10];
  const float* bl      = (const float*)d_in[11];
  const float* sl      = (const float*)d_in[12];
  const float* Wd      = (const float*)d_in[13];
  const float* bd      = (const float*)d_in[14];
  const float* sd      = (const float*)d_in[15];
  const float* dt_bias = (const float*)d_in[16];
  const float* A_logs  = (const float*)d_in[17];
  const float* Ds      = (const float*)d_in[18];
  const float* ln_w    = (const float*)d_in[19];
  const float* ln_b    = (const float*)d_in[20];
  const float* W_out   = (const float*)d_in[21];
  const float* b_out   = (const float*)d_in[22];
  const float* s_out   = (const float*)d_in[23];
  float* ws  = (float*)d_ws;
  float* out = (float*)d_out;

  hipLaunchKernelGGL(k_prep, dim3(1592), dim3(64), 0, stream,
                     W_in, s_in, W_out, s_out, Wl, sl, Wd, sd, conv_W, ws);
  hipLaunchKernelGGL(k_bilin_in, dim3(2048), dim3(384), 0, stream,
                     x, b_in, ws, ws + OFF_XC, ws + OFF_ZS);
  // zero padded bit-planes, then pack
  hipMemsetAsync((void*)(ws + OFF_XB), 0, (size_t)(4 * 6 * PLANE) * sizeof(float), stream);
  hipLaunchKernelGGL(k_pack, dim3(192), dim3(256), 0, stream,
                     ws + OFF_XC, move0_b, (uint32_t*)(ws + OFF_XB));
  hipLaunchKernelGGL(k_conv, dim3(256), dim3(256), 0, stream,
                     (const uint32_t*)(ws + OFF_XB), ws + OFF_XC,
                     (const uint32_t*)(ws + OFF_WCS), (const int*)(ws + OFF_WAUX),
                     ws + OFF_WSC, conv_b, rp_b0, prelu_a, rp_b1,
                     ws + OFF_XCONV);
  hipLaunchKernelGGL(k_build_xs, dim3(49152), dim3(256), 0, stream,
                     ws + OFF_XCONV, ws + OFF_XS);
  hipLaunchKernelGGL(k_xdbl, dim3(2048), dim3(256), 0, stream,
                     ws + OFF_XS, ws, bl, ws + OFF_XDBL);
  // chunked parallel scan
  hipLaunchKernelGGL(k_scan_a, dim3(1024), dim3(192), 0, stream,
                     ws + OFF_XS, ws + OFF_XDBL, ws, bd, dt_bias, A_logs,
                     ws + OFF_HEND, ws + OFF_SSUM);
  hipLaunchKernelGGL(k_scan_b, dim3(192), dim3(256), 0, stream,
                     A_logs, ws + OFF_SSUM, ws + OFF_HEND);
  hipMemsetAsync((void*)(ws + OFF_XC), 0, (size_t)3145728 * sizeof(float), stream);
  hipLaunchKernelGGL(k_scan_c, dim3(1024), dim3(192), 0, stream,
                     ws + OFF_XS, ws + OFF_XDBL, ws, bd, dt_bias, A_logs, Ds,
                     ws + OFF_HEND, ws + OFF_XC);
  hipLaunchKernelGGL(k_ln, dim3(256), dim3(256), 0, stream,
                     ws + OFF_XC, ws + OFF_ZS, ln_w, ln_b, ws + OFF_XCONV);
  hipLaunchKernelGGL(k_out, dim3(1024), dim3(256), 0, stream,
                     ws + OFF_XCONV, ws, b_out, out);
}

// Round 5
// 449.952 us; speedup vs baseline: 4.5744x; 1.3764x over previous
//
#include <hip/hip_runtime.h>
#include <math.h>
#include <stdint.h>

// Problem constants
#define BB 4
#define HH 64
#define WW2 64
#define DM 96
#define DN 192
#define KK 4
#define NN 16
#define RR 6
#define LL 4096
#define RN 38   // R + 2N

#define LOG2E 1.4426950408889634f
#define LN2   0.6931471805599453f

// Workspace layout (4-byte units). Peak = 24,923,456 floats = 99.69 MB.
#define OFF_WDB      0           // float[768*6] dts sign weights
#define OFF_WCS      4608        // u32[192*56] packed conv weights
#define OFF_WAUX     15360       // int[192*8] conv border corrections
#define OFF_WSC      16896       // float[192] conv scale
#define OFF_WBIB     17088       // u32[384*3] packed W_in sign bits
#define OFF_WOUTB    18240       // u32[96*6] packed W_out sign bits
#define OFF_WLBB     18816       // u32[152*6] packed Wl sign bits
// shared scratch pool (lifetime-disjoint): 393216 words @ 19728
#define OFF_XBP      19728       // u32[4*6*4356] conv input bit planes (bilin->conv)
#define OFF_PXS      19728       // u32[16*24576] packed sign(xs) flat (build_xs->xdbl)
#define OFF_SSUM     19728       // float[64*3072] chunk delta sums (scan_a->scan_b)
#define OFF_YB       19728       // u32[16384*6] packed sign(ln*silu z) (ln->out)
#define OFF_XC       412992      // float[3145728] xp (B,Dn,L); reused as y accum [b][L][d]
#define OFF_ZS       3558720     // float[3145728] silu(z) (B,L,Dn)
#define OFF_XCONV    6704448     // float[3145728] conv out (B,Dn,L); reused as hend/h0
#define OFF_XS       9850176     // float[12582912] 4-direction scan input
#define OFF_XDBL     22433088    // float[16*38*4096] x_dbl (B,K,38,L)
#define OFF_HEND     OFF_XCONV

#define PLANE 4356   // 66*66

__device__ __forceinline__ float fsign(float v) {
  return (v > 0.f) ? 1.f : ((v < 0.f) ? -1.f : 0.f);
}
__device__ __forceinline__ float softplusf(float v) {
  return fmaxf(v, 0.f) + LN2 * log2f(1.f + exp2f(-fabsf(v) * LOG2E));
}
__device__ __forceinline__ float siluf(float v) {
  return v / (1.f + expf(-v));
}
__device__ __forceinline__ float waveAllSum(float s) {
  #pragma unroll
  for (int off = 32; off; off >>= 1) s += __shfl_xor(s, off, 64);
  return s;
}

// ---------------- prep: pack all sign weights ----------------
__global__ __launch_bounds__(64) void k_prep(
    const float* __restrict__ W_in, const float* __restrict__ s_in,
    const float* __restrict__ W_out, const float* __restrict__ s_out,
    const float* __restrict__ Wl, const float* __restrict__ sl,
    const float* __restrict__ Wd, const float* __restrict__ sd,
    const float* __restrict__ convW, float* __restrict__ ws) {
  int r = blockIdx.x, lane = threadIdx.x;
  if (r < 384) {                 // W_in rows (len 96) -> 3 words
    const float* row = W_in + r * DM;
    float s = 0.f;
    for (int c = lane; c < DM; c += 64) s += row[c];   // FIX: full 96-elem sum
    s = waveAllSum(s);
    float mean = s / (float)DM;
    if (lane < 3) {
      uint32_t wv = 0;
      #pragma unroll
      for (int i = 0; i < 32; ++i) wv |= (row[lane * 32 + i] - mean > 0.f ? 1u : 0u) << i;
      ((uint32_t*)(ws + OFF_WBIB))[r * 3 + lane] = wv;
    }
  } else if (r < 480) {          // W_out rows (len 192) -> 6 words
    int m = r - 384;
    const float* row = W_out + m * DN;
    float s = 0.f;
    for (int c = lane; c < DN; c += 64) s += row[c];
    s = waveAllSum(s);
    float mean = s / (float)DN;
    if (lane < 6) {
      uint32_t wv = 0;
      #pragma unroll
      for (int i = 0; i < 32; ++i) wv |= (row[lane * 32 + i] - mean > 0.f ? 1u : 0u) << i;
      ((uint32_t*)(ws + OFF_WOUTB))[m * 6 + lane] = wv;
    }
  } else if (r < 632) {          // Wl rows (len 192) -> 6 words
    int idx = r - 480;
    const float* row = Wl + idx * DN;
    float s = 0.f;
    for (int c = lane; c < DN; c += 64) s += row[c];
    s = waveAllSum(s);
    float mean = s / (float)DN;
    if (lane < 6) {
      uint32_t wv = 0;
      #pragma unroll
      for (int i = 0; i < 32; ++i) wv |= (row[lane * 32 + i] - mean > 0.f ? 1u : 0u) << i;
      ((uint32_t*)(ws + OFF_WLBB))[idx * 6 + lane] = wv;
    }
  } else if (r < 1400) {         // Wd rows (len 6), keep float
    int idx = r - 632;
    const float* row = Wd + idx * RR;
    float s = (lane < RR) ? row[lane] : 0.f;
    s = waveAllSum(s);
    float mean = s / (float)RR, sc = sd[idx];
    if (lane < RR) (ws + OFF_WDB)[idx * RR + lane] = sc * fsign(row[lane] - mean);
  } else {                       // conv channel o
    int o = r - 1400;
    const float* row = convW + o * 1728;
    float s = 0.f;
    for (int j = lane; j < 1728; j += 64) s += fabsf(row[j]);
    s = waveAllSum(s);
    float sc = s / 1728.f;
    uint32_t* wb = (uint32_t*)(ws + OFF_WCS);
    int* aux = (int*)(ws + OFF_WAUX);
    float* scf = ws + OFF_WSC;
    uint32_t word = 0;
    if (lane < 54) {
      int cw = lane / 9, tap = lane % 9;
      #pragma unroll
      for (int i = 0; i < 32; ++i)
        word |= (row[(cw * 32 + i) * 9 + tap] > 0.f ? 1u : 0u) << i;
      wb[o * 56 + lane] = word;
    } else if (lane < 56) {
      wb[o * 56 + lane] = 0u;
    }
    int pc = (lane < 54) ? 2 * (int)__popc(word) - 32 : 0;
    int tapid = lane % 9;
    int wst = 0;
    #pragma unroll
    for (int cw = 0; cw < 6; ++cw) wst += __shfl(pc, cw * 9 + tapid, 64);
    int w_t[9];
    #pragma unroll
    for (int t9 = 0; t9 < 9; ++t9) w_t[t9] = __shfl(wst, t9, 64);
    if (lane == 0) {
      aux[o * 8 + 0] = w_t[0] + w_t[3] + w_t[6];
      aux[o * 8 + 1] = w_t[2] + w_t[5] + w_t[8];
      aux[o * 8 + 2] = w_t[0] + w_t[1] + w_t[2];
      aux[o * 8 + 3] = w_t[6] + w_t[7] + w_t[8];
      aux[o * 8 + 4] = w_t[0];
      aux[o * 8 + 5] = w_t[2];
      aux[o * 8 + 6] = w_t[6];
      aux[o * 8 + 7] = w_t[8];
      scf[o] = sc;
    }
  }
}

// ---------------- input bilinear via XOR-popcount ----------------
__global__ __launch_bounds__(384) void k_bilin_in(
    const float* __restrict__ x, const float* __restrict__ b_in,
    const float* __restrict__ s_in, const float* __restrict__ ws,
    float* __restrict__ xc, float* __restrict__ zs) {
  __shared__ uint32_t spx[16 * 3];
  int p0 = blockIdx.x * 16;
  if (threadIdx.x < 48) {
    int pix = threadIdx.x / 3, wd = threadIdx.x % 3;
    const float* base = x + (size_t)(p0 + pix) * DM + wd * 32;
    uint32_t wv = 0;
    #pragma unroll
    for (int i = 0; i < 32; ++i) wv |= (base[i] > 0.f ? 1u : 0u) << i;
    spx[pix * 3 + wd] = wv;
  }
  __syncthreads();
  int o = threadIdx.x;
  uint32_t w0, w1, w2;
  {
    const uint32_t* wb = (const uint32_t*)(ws + OFF_WBIB) + o * 3;
    w0 = wb[0]; w1 = wb[1]; w2 = wb[2];
  }
  float bias = b_in[o], sc = s_in[o];
  int b = p0 >> 12, l0 = p0 & 4095;
  #pragma unroll
  for (int pix = 0; pix < 16; ++pix) {
    int P = (int)__popc(spx[pix * 3 + 0] ^ w0) + (int)__popc(spx[pix * 3 + 1] ^ w1) +
            (int)__popc(spx[pix * 3 + 2] ^ w2);
    float acc = bias + sc * (float)(DM - 2 * P);
    if (o < DN) xc[((size_t)(b * DN + o)) * LL + l0 + pix] = acc;
    else        zs[(size_t)(p0 + pix) * DN + (o - DN)] = siluf(acc);
  }
}

// ---------------- pack sign(xc+move0) into zero-padded bit-planes ----------------
__global__ __launch_bounds__(256) void k_pack(
    const float* __restrict__ xc, const float* __restrict__ move0,
    uint32_t* __restrict__ xb) {
  int t = blockIdx.x * 256 + threadIdx.x;
  int w2 = t & 31;
  int h = (t >> 5) & 63;
  int g = t >> 11;
  int cw = g % 6, b = g / 6;
  const float* xp = xc + ((size_t)(b * DN + cw * 32)) * LL + h * 64 + w2 * 2;
  uint32_t w0 = 0, w1 = 0;
  #pragma unroll
  for (int i = 0; i < 32; ++i) {
    float m = move0[cw * 32 + i];
    float2 v = *(const float2*)(xp + (size_t)i * LL);
    w0 |= (v.x + m > 0.f ? 1u : 0u) << i;
    w1 |= (v.y + m > 0.f ? 1u : 0u) << i;
  }
  uint32_t* plane = xb + (size_t)(b * 6 + cw) * PLANE;
  plane[(h + 1) * 66 + 1 + w2 * 2] = w0;
  plane[(h + 1) * 66 + 2 + w2 * 2] = w1;
}

// ---------------- XNOR-popcount binary 3x3 conv + RPReLU + residual + SiLU ----------------
__global__ __launch_bounds__(256) void k_conv(
    const uint32_t* __restrict__ xb, const float* __restrict__ xc,
    const uint32_t* __restrict__ wbits, const int* __restrict__ aux,
    const float* __restrict__ scf, const float* __restrict__ conv_b,
    const float* __restrict__ rp_b0, const float* __restrict__ prelu_a,
    const float* __restrict__ rp_b1, float* __restrict__ xconv) {
  int og = blockIdx.x & 3;
  int stripe = (blockIdx.x >> 2) & 15;
  int b = blockIdx.x >> 6;
  int w = threadIdx.x & 63, r = threadIdx.x >> 6;
  int h = stripe * 4 + r;

  __shared__ uint32_t swb[48 * 56];
  __shared__ int saux[48 * 8];
  __shared__ float sconst[48 * 4];
  for (int i = threadIdx.x; i < 48 * 56; i += 256) swb[i] = wbits[og * (48 * 56) + i];
  for (int i = threadIdx.x; i < 48 * 8; i += 256) saux[i] = aux[og * (48 * 8) + i];
  if (threadIdx.x < 48) {
    int o = og * 48 + threadIdx.x;
    sconst[threadIdx.x * 4 + 0] = scf[o];
    sconst[threadIdx.x * 4 + 1] = conv_b[o] + rp_b0[o];
    sconst[threadIdx.x * 4 + 2] = prelu_a[o];
    sconst[threadIdx.x * 4 + 3] = rp_b1[o];
  }

  uint32_t xw[6][9];
  const uint32_t* xpb = xb + (size_t)b * 6 * PLANE;
  #pragma unroll
  for (int cw = 0; cw < 6; ++cw) {
    const uint32_t* plane = xpb + cw * PLANE + (h + 1) * 66 + (w + 1);
    #pragma unroll
    for (int dy = 0; dy < 3; ++dy) {
      #pragma unroll
      for (int dx = 0; dx < 3; ++dx)
        xw[cw][dy * 3 + dx] = plane[(dy - 1) * 66 + (dx - 1)];
    }
  }
  bool isL = (w == 0), isR = (w == 63);
  bool isT = (h == 0), isB = (h == 63);
  const float* xcp = xc + ((size_t)(b * DN + og * 48)) * LL + h * 64 + w;
  float* xop = xconv + ((size_t)(b * DN + og * 48)) * LL + h * 64 + w;
  __syncthreads();

  #pragma unroll 1
  for (int oc = 0; oc < 48; ++oc) {
    const uint32_t* wp = &swb[oc * 56];
    int P = 0;
    #pragma unroll
    for (int cw = 0; cw < 6; ++cw) {
      int pp = 0;
      #pragma unroll
      for (int t = 0; t < 9; ++t) pp += (int)__popc(wp[cw * 9 + t] ^ xw[cw][t]);
      P += pp;
    }
    int corr = isL ? saux[oc * 8 + 0] : (isR ? saux[oc * 8 + 1] : 0);
    if (isT) {
      corr += saux[oc * 8 + 2];
      if (isL) corr -= saux[oc * 8 + 4];
      if (isR) corr -= saux[oc * 8 + 5];
    }
    if (isB) {
      corr += saux[oc * 8 + 3];
      if (isL) corr -= saux[oc * 8 + 6];
      if (isR) corr -= saux[oc * 8 + 7];
    }
    float acc = sconst[oc * 4 + 0] * (float)(1728 - 2 * P + corr);
    float t = acc + sconst[oc * 4 + 1];
    t = (t >= 0.f) ? t : sconst[oc * 4 + 2] * t;
    t += sconst[oc * 4 + 3] + *xcp;
    *xop = siluf(t);
    xcp += LL; xop += LL;
  }
}

// ---------------- build xs + pack flat sign bits via ballot ----------------
__global__ __launch_bounds__(256) void k_build_xs(const float* __restrict__ xconv,
                                                  float* __restrict__ xs,
                                                  uint32_t* __restrict__ pxs) {
  int idx = blockIdx.x * 256 + threadIdx.x;
  int l = idx & 4095;
  int d = (idx >> 12) % DN;
  int k = ((idx >> 12) / DN) % KK;
  int b = idx / (KK * DN * LL);
  int src;
  if (k == 0)      src = l;
  else if (k == 1) src = ((l & 63) << 6) | (l >> 6);
  else if (k == 2) src = 4095 - l;
  else { int t2 = 4095 - l; src = ((t2 & 63) << 6) | (t2 >> 6); }
  float v = xconv[(b * DN + d) * LL + src];
  xs[idx] = v;
  unsigned long long m = __ballot(v > 0.f);
  int lane = threadIdx.x & 63;
  if (lane == 0)       pxs[idx >> 5] = (uint32_t)m;
  else if (lane == 32) pxs[idx >> 5] = (uint32_t)(m >> 32);
}

// ---------------- x_dbl via XOR-popcount (raw-reshape rows = flat 192-chunks) ----------------
__global__ __launch_bounds__(256) void k_xdbl(
    const uint32_t* __restrict__ pxs, const float* __restrict__ ws,
    const float* __restrict__ bl, const float* __restrict__ sl,
    float* __restrict__ xdbl) {
  int bk = blockIdx.x >> 4;
  int l = ((blockIdx.x & 15) << 8) + threadIdx.x;
  int k = bk & 3;
  __shared__ uint32_t swl[RN * 6];
  __shared__ float sbias[RN], ssc[RN];
  if (threadIdx.x < RN * 6) swl[threadIdx.x] = ((const uint32_t*)(ws + OFF_WLBB))[k * RN * 6 + threadIdx.x];
  if (threadIdx.x < RN) {
    sbias[threadIdx.x] = bl[k * RN + threadIdx.x];
    ssc[threadIdx.x] = sl[k * RN + threadIdx.x];
  }
  uint32_t xb[6];
  const uint32_t* pp = pxs + (size_t)bk * 24576 + (size_t)l * 6;
  #pragma unroll
  for (int j = 0; j < 6; ++j) xb[j] = pp[j];
  __syncthreads();
  float* xo = xdbl + (size_t)bk * (RN * LL) + l;
  #pragma unroll 1
  for (int o = 0; o < RN; ++o) {
    int P = 0;
    #pragma unroll
    for (int j = 0; j < 6; ++j) P += (int)__popc(xb[j] ^ swl[o * 6 + j]);
    xo[(size_t)o * LL] = sbias[o] + ssc[o] * (float)(DN - 2 * P);
  }
}

// ---------------- scan pass A ----------------
__global__ __launch_bounds__(192) void k_scan_a(
    const float* __restrict__ xs, const float* __restrict__ xdbl,
    const float* __restrict__ ws, const float* __restrict__ bd,
    const float* __restrict__ dt_bias, const float* __restrict__ A_logs,
    float* __restrict__ hend, float* __restrict__ Ssum) {
  int c = blockIdx.x & 63;
  int bk = blockIdx.x >> 6;
  int k = bk & 3;
  int d = threadIdx.x;
  int t0 = c << 6;
  __shared__ float sdt[384];
  __shared__ float4 sB4[256];
  float* sBf = (float*)sB4;
  const float* dtbase = xdbl + (size_t)bk * (RN * LL);
  for (int i = d; i < 384; i += 192) sdt[i] = fsign(dtbase[t0 * 6 + i]);
  {
    const float4* Bp = (const float4*)(xdbl + ((size_t)bk * RN + RR) * LL);
    for (int i = d; i < 256; i += 192) {
      int n = i >> 4, j = i & 15;
      float4 v = Bp[n * 1024 + (t0 >> 2) + j];
      sBf[(4 * j + 0) * 16 + n] = v.x;
      sBf[(4 * j + 1) * 16 + n] = v.y;
      sBf[(4 * j + 2) * 16 + n] = v.z;
      sBf[(4 * j + 3) * 16 + n] = v.w;
    }
  }
  float wd[6];
  {
    const float* wdp = ws + OFF_WDB + (k * DN + d) * RR;
    #pragma unroll
    for (int r = 0; r < RR; ++r) wd[r] = wdp[r];
  }
  float biasd = bd[k * DN + d] + dt_bias[k * DN + d];
  float An[16];
  {
    const float* ap = A_logs + (k * DN + d) * NN;
    #pragma unroll
    for (int n = 0; n < NN; ++n) An[n] = -expf(ap[n]) * LOG2E;
  }
  float h[16];
  #pragma unroll
  for (int n = 0; n < NN; ++n) h[n] = 0.f;
  float S = 0.f;
  const float* up = xs + ((size_t)bk * DN + d) * LL + t0;
  __syncthreads();
  #pragma unroll 1
  for (int tt = 0; tt < 16; ++tt) {
    float4 u4 = *(const float4*)(up + 4 * tt);
    #pragma unroll
    for (int q = 0; q < 4; ++q) {
      int t = 4 * tt + q;
      float uv = (q == 0) ? u4.x : (q == 1) ? u4.y : (q == 2) ? u4.z : u4.w;
      float acc = biasd;
      #pragma unroll
      for (int r = 0; r < RR; ++r) acc += sdt[t * 6 + r] * wd[r];
      float dv = softplusf(acc);
      S += dv;
      float du = dv * uv;
      #pragma unroll
      for (int g = 0; g < 4; ++g) {
        float4 bv = sB4[t * 4 + g];
        float a0 = exp2f(dv * An[4 * g + 0]);
        float a1 = exp2f(dv * An[4 * g + 1]);
        float a2 = exp2f(dv * An[4 * g + 2]);
        float a3 = exp2f(dv * An[4 * g + 3]);
        h[4 * g + 0] = a0 * h[4 * g + 0] + du * bv.x;
        h[4 * g + 1] = a1 * h[4 * g + 1] + du * bv.y;
        h[4 * g + 2] = a2 * h[4 * g + 2] + du * bv.z;
        h[4 * g + 3] = a3 * h[4 * g + 3] + du * bv.w;
      }
    }
  }
  float* hp = hend + (size_t)c * 49152 + (size_t)(bk * DN + d) * 16;
  #pragma unroll
  for (int n = 0; n < NN; n += 4)
    *(float4*)(hp + n) = make_float4(h[n], h[n + 1], h[n + 2], h[n + 3]);
  Ssum[c * 3072 + bk * DN + d] = S;
}

// ---------------- scan pass B ----------------
__global__ __launch_bounds__(256) void k_scan_b(
    const float* __restrict__ A_logs, const float* __restrict__ Ssum,
    float* __restrict__ hend) {
  int tid = blockIdx.x * 256 + threadIdx.x;
  int bkd = tid >> 4, n = tid & 15;
  int bk = bkd / DN, d = bkd - bk * DN;
  int k = bk & 3;
  float An2 = -expf(A_logs[(k * DN + d) * NN + n]) * LOG2E;
  float h = 0.f;
  float Sc = Ssum[bkd];
  float he = hend[tid];
  #pragma unroll 1
  for (int c = 0; c < 64; ++c) {
    float Sn = 0.f, hn = 0.f;
    if (c < 63) {
      Sn = Ssum[(c + 1) * 3072 + bkd];
      hn = hend[(size_t)(c + 1) * 49152 + tid];
    }
    hend[(size_t)c * 49152 + tid] = h;
    h = exp2f(An2 * Sc) * h + he;
    Sc = Sn; he = hn;
  }
}

// ---------------- scan pass C ----------------
__global__ __launch_bounds__(192) void k_scan_c(
    const float* __restrict__ xs, const float* __restrict__ xdbl,
    const float* __restrict__ ws, const float* __restrict__ bd,
    const float* __restrict__ dt_bias, const float* __restrict__ A_logs,
    const float* __restrict__ Ds, const float* __restrict__ h0buf,
    float* __restrict__ y) {
  int c = blockIdx.x & 63;
  int bk = blockIdx.x >> 6;
  int k = bk & 3;
  int d = threadIdx.x;
  int t0 = c << 6;
  __shared__ float sdt[384];
  __shared__ float4 sB4[256];
  __shared__ float4 sC4[256];
  float* sBf = (float*)sB4;
  float* sCf = (float*)sC4;
  const float* dtbase = xdbl + (size_t)bk * (RN * LL);
  for (int i = d; i < 384; i += 192) sdt[i] = fsign(dtbase[t0 * 6 + i]);
  {
    const float4* Bp = (const float4*)(xdbl + ((size_t)bk * RN + RR) * LL);
    const float4* Cp = (const float4*)(xdbl + ((size_t)bk * RN + RR + NN) * LL);
    for (int i = d; i < 256; i += 192) {
      int n = i >> 4, j = i & 15;
      float4 v = Bp[n * 1024 + (t0 >> 2) + j];
      sBf[(4 * j + 0) * 16 + n] = v.x;
      sBf[(4 * j + 1) * 16 + n] = v.y;
      sBf[(4 * j + 2) * 16 + n] = v.z;
      sBf[(4 * j + 3) * 16 + n] = v.w;
      float4 w = Cp[n * 1024 + (t0 >> 2) + j];
      sCf[(4 * j + 0) * 16 + n] = w.x;
      sCf[(4 * j + 1) * 16 + n] = w.y;
      sCf[(4 * j + 2) * 16 + n] = w.z;
      sCf[(4 * j + 3) * 16 + n] = w.w;
    }
  }
  float wd[6];
  {
    const float* wdp = ws + OFF_WDB + (k * DN + d) * RR;
    #pragma unroll
    for (int r = 0; r < RR; ++r) wd[r] = wdp[r];
  }
  float biasd = bd[k * DN + d] + dt_bias[k * DN + d];
  float Dd = Ds[k * DN + d];
  float An[16];
  {
    const float* ap = A_logs + (k * DN + d) * NN;
    #pragma unroll
    for (int n = 0; n < NN; ++n) An[n] = -expf(ap[n]) * LOG2E;
  }
  float h[16];
  {
    const float* hp = h0buf + (size_t)c * 49152 + (size_t)(bk * DN + d) * 16;
    #pragma unroll
    for (int n = 0; n < NN; n += 4) {
      float4 v = *(const float4*)(hp + n);
      h[n] = v.x; h[n + 1] = v.y; h[n + 2] = v.z; h[n + 3] = v.w;
    }
  }
  const float* up = xs + ((size_t)bk * DN + d) * LL + t0;
  float* yb = y + (size_t)(bk >> 2) * (LL * DN);
  __syncthreads();
  #pragma unroll 1
  for (int tt = 0; tt < 16; ++tt) {
    float4 u4 = *(const float4*)(up + 4 * tt);
    #pragma unroll
    for (int q = 0; q < 4; ++q) {
      int t = 4 * tt + q;
      float uv = (q == 0) ? u4.x : (q == 1) ? u4.y : (q == 2) ? u4.z : u4.w;
      float acc = biasd;
      #pragma unroll
      for (int r = 0; r < RR; ++r) acc += sdt[t * 6 + r] * wd[r];
      float dv = softplusf(acc);
      float du = dv * uv;
      float yv = Dd * uv;
      #pragma unroll
      for (int g = 0; g < 4; ++g) {
        float4 bv = sB4[t * 4 + g];
        float4 cv = sC4[t * 4 + g];
        float a0 = exp2f(dv * An[4 * g + 0]);
        float a1 = exp2f(dv * An[4 * g + 1]);
        float a2 = exp2f(dv * An[4 * g + 2]);
        float a3 = exp2f(dv * An[4 * g + 3]);
        h[4 * g + 0] = a0 * h[4 * g + 0] + du * bv.x;
        h[4 * g + 1] = a1 * h[4 * g + 1] + du * bv.y;
        h[4 * g + 2] = a2 * h[4 * g + 2] + du * bv.z;
        h[4 * g + 3] = a3 * h[4 * g + 3] + du * bv.w;
        yv += cv.x * h[4 * g + 0];
        yv += cv.y * h[4 * g + 1];
        yv += cv.z * h[4 * g + 2];
        yv += cv.w * h[4 * g + 3];
      }
      int ta = t0 + t, l;
      if (k == 0)      l = ta;
      else if (k == 1) l = ((ta & 63) << 6) | (ta >> 6);
      else if (k == 2) l = 4095 - ta;
      else { int t2 = 4095 - ta; l = ((t2 & 63) << 6) | (t2 >> 6); }
      atomicAdd(&yb[(size_t)l * DN + d], yv);
    }
  }
}

// ---------------- LayerNorm over Dn + * silu(z) -> packed sign bits ----------------
__global__ __launch_bounds__(256) void k_ln(
    const float* __restrict__ y, const float* __restrict__ zs,
    const float* __restrict__ ln_w, const float* __restrict__ ln_b,
    uint32_t* __restrict__ ybits) {
  __shared__ float ty[64 * 193];
  __shared__ float ps[256];
  __shared__ float smu[64], srs[64];
  __shared__ float slw[DN], slb[DN];
  int b = blockIdx.x >> 6;
  int l0 = (blockIdx.x & 63) << 6;
  const float* yp = y + (size_t)(b * LL + l0) * DN;
  if (threadIdx.x < DN) {
    slw[threadIdx.x] = ln_w[threadIdx.x];
    slb[threadIdx.x] = ln_b[threadIdx.x];
  }
  {
    int lc = threadIdx.x / DN, d2 = threadIdx.x - lc * DN;
    for (int i = threadIdx.x; i < 64 * DN; i += 256) {
      ty[lc * 193 + d2] = yp[i];
      d2 += 256;
      if (d2 >= DN) { d2 -= DN; lc += 1; if (d2 >= DN) { d2 -= DN; lc += 1; } }
    }
  }
  __syncthreads();
  int lc = threadIdx.x & 63, part = threadIdx.x >> 6;
  float s = 0.f;
  for (int d = part * 48; d < part * 48 + 48; ++d) s += ty[lc * 193 + d];
  ps[threadIdx.x] = s;
  __syncthreads();
  if (threadIdx.x < 64)
    smu[threadIdx.x] = (ps[threadIdx.x] + ps[threadIdx.x + 64] +
                        ps[threadIdx.x + 128] + ps[threadIdx.x + 192]) / (float)DN;
  __syncthreads();
  float mu = smu[lc];
  float q = 0.f;
  for (int d = part * 48; d < part * 48 + 48; ++d) {
    float v = ty[lc * 193 + d] - mu; q += v * v;
  }
  ps[threadIdx.x] = q;
  __syncthreads();
  if (threadIdx.x < 64) {
    float var = (ps[threadIdx.x] + ps[threadIdx.x + 64] +
                 ps[threadIdx.x + 128] + ps[threadIdx.x + 192]) / (float)DN;
    srs[threadIdx.x] = rsqrtf(var + 1e-5f);
  }
  __syncthreads();
  for (int item = threadIdx.x; item < 64 * 6; item += 256) {
    int lc2 = item / 6, wd = item % 6;
    float mu2 = smu[lc2], rs2 = srs[lc2];
    const float* zb = zs + (size_t)(b * LL + l0 + lc2) * DN + wd * 32;
    uint32_t wv = 0;
    #pragma unroll
    for (int i = 0; i < 32; ++i) {
      int d = wd * 32 + i;
      float ln = (ty[lc2 * 193 + d] - mu2) * rs2 * slw[d] + slb[d];
      wv |= ((ln * zb[i] > 0.f) ? 1u : 0u) << i;
    }
    ybits[(size_t)(b * LL + l0 + lc2) * 6 + wd] = wv;
  }
}

// ---------------- output bilinear via XOR-popcount ----------------
__global__ __launch_bounds__(256) void k_out(
    const uint32_t* __restrict__ ybits, const float* __restrict__ ws,
    const float* __restrict__ b_out, const float* __restrict__ s_out,
    float* __restrict__ out) {
  __shared__ uint32_t sy[64 * 6];
  __shared__ uint32_t swo[96 * 6];
  __shared__ float sb[96], ssc[96];
  int p0 = blockIdx.x * 64;
  for (int i = threadIdx.x; i < 64 * 6; i += 256) sy[i] = ybits[(size_t)p0 * 6 + i];
  for (int i = threadIdx.x; i < 96 * 6; i += 256) swo[i] = ((const uint32_t*)(ws + OFF_WOUTB))[i];
  if (threadIdx.x < 96) {
    sb[threadIdx.x] = b_out[threadIdx.x];
    ssc[threadIdx.x] = s_out[threadIdx.x];
  }
  __syncthreads();
  for (int oi = threadIdx.x; oi < 64 * DM; oi += 256) {
    int pr = oi / DM, m = oi % DM;
    int P = 0;
    #pragma unroll
    for (int j = 0; j < 6; ++j) P += (int)__popc(sy[pr * 6 + j] ^ swo[m * 6 + j]);
    out[(size_t)(p0 + pr) * DM + m] = sb[m] + ssc[m] * (float)(DN - 2 * P);
  }
}

extern "C" void kernel_launch(void* const* d_in, const int* in_sizes, int n_in,
                              void* d_out, int out_size, void* d_ws, size_t ws_size,
                              hipStream_t stream) {
  const float* x       = (const float*)d_in[0];
  const float* W_in    = (const float*)d_in[1];
  const float* b_in    = (const float*)d_in[2];
  const float* s_in    = (const float*)d_in[3];
  const float* move0_b = (const float*)d_in[4];
  const float* conv_W  = (const float*)d_in[5];
  const float* conv_b  = (const float*)d_in[6];
  const float* rp_b0   = (const float*)d_in[7];
  const float* prelu_a = (const float*)d_in[8];
  const float* rp_b1   = (const float*)d_in[9];
  const float* Wl      = (const float*)d_in[10];
  const float* bl      = (const float*)d_in[11];
  const float* sl      = (const float*)d_in[12];
  const float* Wd      = (const float*)d_in[13];
  const float* bd      = (const float*)d_in[14];
  const float* sd      = (const float*)d_in[15];
  const float* dt_bias = (const float*)d_in[16];
  const float* A_logs  = (const float*)d_in[17];
  const float* Ds      = (const float*)d_in[18];
  const float* ln_w    = (const float*)d_in[19];
  const float* ln_b    = (const float*)d_in[20];
  const float* W_out   = (const float*)d_in[21];
  const float* b_out   = (const float*)d_in[22];
  const float* s_out   = (const float*)d_in[23];
  float* ws  = (float*)d_ws;
  float* out = (float*)d_out;

  hipLaunchKernelGGL(k_prep, dim3(1592), dim3(64), 0, stream,
                     W_in, s_in, W_out, s_out, Wl, sl, Wd, sd, conv_W, ws);
  hipLaunchKernelGGL(k_bilin_in, dim3(1024), dim3(384), 0, stream,
                     x, b_in, s_in, ws, ws + OFF_XC, ws + OFF_ZS);
  hipMemsetAsync((void*)(ws + OFF_XBP), 0, (size_t)(4 * 6 * PLANE) * 4, stream);
  hipLaunchKernelGGL(k_pack, dim3(192), dim3(256), 0, stream,
                     ws + OFF_XC, move0_b, (uint32_t*)(ws + OFF_XBP));
  hipLaunchKernelGGL(k_conv, dim3(256), dim3(256), 0, stream,
                     (const uint32_t*)(ws + OFF_XBP), ws + OFF_XC,
                     (const uint32_t*)(ws + OFF_WCS), (const int*)(ws + OFF_WAUX),
                     ws + OFF_WSC, conv_b, rp_b0, prelu_a, rp_b1,
                     ws + OFF_XCONV);
  hipLaunchKernelGGL(k_build_xs, dim3(49152), dim3(256), 0, stream,
                     ws + OFF_XCONV, ws + OFF_XS, (uint32_t*)(ws + OFF_PXS));
  hipLaunchKernelGGL(k_xdbl, dim3(256), dim3(256), 0, stream,
                     (const uint32_t*)(ws + OFF_PXS), ws, bl, sl, ws + OFF_XDBL);
  hipLaunchKernelGGL(k_scan_a, dim3(1024), dim3(192), 0, stream,
                     ws + OFF_XS, ws + OFF_XDBL, ws, bd, dt_bias, A_logs,
                     ws + OFF_HEND, ws + OFF_SSUM);
  hipLaunchKernelGGL(k_scan_b, dim3(192), dim3(256), 0, stream,
                     A_logs, ws + OFF_SSUM, ws + OFF_HEND);
  hipMemsetAsync((void*)(ws + OFF_XC), 0, (size_t)3145728 * sizeof(float), stream);
  hipLaunchKernelGGL(k_scan_c, dim3(1024), dim3(192), 0, stream,
                     ws + OFF_XS, ws + OFF_XDBL, ws, bd, dt_bias, A_logs, Ds,
                     ws + OFF_HEND, ws + OFF_XC);
  hipLaunchKernelGGL(k_ln, dim3(256), dim3(256), 0, stream,
                     ws + OFF_XC, ws + OFF_ZS, ln_w, ln_b, (uint32_t*)(ws + OFF_YB));
  hipLaunchKernelGGL(k_out, dim3(256), dim3(256), 0, stream,
                     (const uint32_t*)(ws + OFF_YB), ws, b_out, s_out, out);
}

// Round 6
// 352.850 us; speedup vs baseline: 5.8333x; 1.2752x over previous
//
#include <hip/hip_runtime.h>
#include <math.h>
#include <stdint.h>

// Problem constants
#define BB 4
#define HH 64
#define WW2 64
#define DM 96
#define DN 192
#define KK 4
#define NN 16
#define RR 6
#define LL 4096
#define RN 38   // R + 2N

#define LOG2E 1.4426950408889634f
#define LN2   0.6931471805599453f

// Workspace layout (4-byte units). Peak = 24,923,456 floats = 99.69 MB.
#define OFF_WDB      0           // float[768*6] dts sign weights
#define OFF_WCS      4608        // u32[192*56] packed conv weights
#define OFF_WAUX     15360       // int[192*8] conv border corrections
#define OFF_WSC      16896       // float[192] conv scale
#define OFF_WBIB     17088       // u32[384*3] packed W_in sign bits
#define OFF_WOUTB    18240       // u32[96*6] packed W_out sign bits
#define OFF_WLBB     18816       // u32[152*6] packed Wl sign bits
// shared scratch pool (lifetime-disjoint): 393216 words @ 19728
#define OFF_XBP      19728       // u32[4*6*4356] conv input bit planes
#define OFF_PXS      19728       // u32[16*24576] packed sign(xs) flat
#define OFF_SSUM     19728       // float[64*3072] chunk delta sums
#define OFF_YB       19728       // u32[16384*6] packed sign(ln*silu z)
#define OFF_XC       412992      // float[3145728] xp (B,Dn,L); reused as y accum [b][L][d]
#define OFF_ZS       3558720     // float[3145728] silu(z) (B,L,Dn)
#define OFF_XCONV    6704448     // float[3145728] conv out (B,Dn,L); reused as hend/h0
#define OFF_XS       9850176     // float[12582912] 4-direction scan input
#define OFF_XDBL     22433088    // float[16*38*4096] x_dbl (B,K,38,L)
#define OFF_HEND     OFF_XCONV

#define PLANE 4356   // 66*66

__device__ __forceinline__ float fsign(float v) {
  return (v > 0.f) ? 1.f : ((v < 0.f) ? -1.f : 0.f);
}
__device__ __forceinline__ float softplusf(float v) {
  return fmaxf(v, 0.f) + LN2 * log2f(1.f + exp2f(-fabsf(v) * LOG2E));
}
__device__ __forceinline__ float siluf(float v) {
  return v / (1.f + expf(-v));
}
__device__ __forceinline__ float waveAllSum(float s) {
  #pragma unroll
  for (int off = 32; off; off >>= 1) s += __shfl_xor(s, off, 64);
  return s;
}

// ---------------- prep: pack all sign weights ----------------
__global__ __launch_bounds__(64) void k_prep(
    const float* __restrict__ W_in, const float* __restrict__ s_in,
    const float* __restrict__ W_out, const float* __restrict__ s_out,
    const float* __restrict__ Wl, const float* __restrict__ sl,
    const float* __restrict__ Wd, const float* __restrict__ sd,
    const float* __restrict__ convW, float* __restrict__ ws) {
  int r = blockIdx.x, lane = threadIdx.x;
  if (r < 384) {                 // W_in rows (len 96) -> 3 words
    const float* row = W_in + r * DM;
    float s = 0.f;
    for (int c = lane; c < DM; c += 64) s += row[c];
    s = waveAllSum(s);
    float mean = s / (float)DM;
    if (lane < 3) {
      uint32_t wv = 0;
      #pragma unroll
      for (int i = 0; i < 32; ++i) wv |= (row[lane * 32 + i] - mean > 0.f ? 1u : 0u) << i;
      ((uint32_t*)(ws + OFF_WBIB))[r * 3 + lane] = wv;
    }
  } else if (r < 480) {          // W_out rows (len 192) -> 6 words
    int m = r - 384;
    const float* row = W_out + m * DN;
    float s = 0.f;
    for (int c = lane; c < DN; c += 64) s += row[c];
    s = waveAllSum(s);
    float mean = s / (float)DN;
    if (lane < 6) {
      uint32_t wv = 0;
      #pragma unroll
      for (int i = 0; i < 32; ++i) wv |= (row[lane * 32 + i] - mean > 0.f ? 1u : 0u) << i;
      ((uint32_t*)(ws + OFF_WOUTB))[m * 6 + lane] = wv;
    }
  } else if (r < 632) {          // Wl rows (len 192) -> 6 words
    int idx = r - 480;
    const float* row = Wl + idx * DN;
    float s = 0.f;
    for (int c = lane; c < DN; c += 64) s += row[c];
    s = waveAllSum(s);
    float mean = s / (float)DN;
    if (lane < 6) {
      uint32_t wv = 0;
      #pragma unroll
      for (int i = 0; i < 32; ++i) wv |= (row[lane * 32 + i] - mean > 0.f ? 1u : 0u) << i;
      ((uint32_t*)(ws + OFF_WLBB))[idx * 6 + lane] = wv;
    }
  } else if (r < 1400) {         // Wd rows (len 6), keep float
    int idx = r - 632;
    const float* row = Wd + idx * RR;
    float s = (lane < RR) ? row[lane] : 0.f;
    s = waveAllSum(s);
    float mean = s / (float)RR, sc = sd[idx];
    if (lane < RR) (ws + OFF_WDB)[idx * RR + lane] = sc * fsign(row[lane] - mean);
  } else {                       // conv channel o
    int o = r - 1400;
    const float* row = convW + o * 1728;
    float s = 0.f;
    for (int j = lane; j < 1728; j += 64) s += fabsf(row[j]);
    s = waveAllSum(s);
    float sc = s / 1728.f;
    uint32_t* wb = (uint32_t*)(ws + OFF_WCS);
    int* aux = (int*)(ws + OFF_WAUX);
    float* scf = ws + OFF_WSC;
    uint32_t word = 0;
    if (lane < 54) {
      int cw = lane / 9, tap = lane % 9;
      #pragma unroll
      for (int i = 0; i < 32; ++i)
        word |= (row[(cw * 32 + i) * 9 + tap] > 0.f ? 1u : 0u) << i;
      wb[o * 56 + lane] = word;
    } else if (lane < 56) {
      wb[o * 56 + lane] = 0u;
    }
    int pc = (lane < 54) ? 2 * (int)__popc(word) - 32 : 0;
    int tapid = lane % 9;
    int wst = 0;
    #pragma unroll
    for (int cw = 0; cw < 6; ++cw) wst += __shfl(pc, cw * 9 + tapid, 64);
    int w_t[9];
    #pragma unroll
    for (int t9 = 0; t9 < 9; ++t9) w_t[t9] = __shfl(wst, t9, 64);
    if (lane == 0) {
      aux[o * 8 + 0] = w_t[0] + w_t[3] + w_t[6];
      aux[o * 8 + 1] = w_t[2] + w_t[5] + w_t[8];
      aux[o * 8 + 2] = w_t[0] + w_t[1] + w_t[2];
      aux[o * 8 + 3] = w_t[6] + w_t[7] + w_t[8];
      aux[o * 8 + 4] = w_t[0];
      aux[o * 8 + 5] = w_t[2];
      aux[o * 8 + 6] = w_t[6];
      aux[o * 8 + 7] = w_t[8];
      scf[o] = sc;
    }
  }
}

// ---------------- input bilinear via XOR-popcount ----------------
__global__ __launch_bounds__(384) void k_bilin_in(
    const float* __restrict__ x, const float* __restrict__ b_in,
    const float* __restrict__ s_in, const float* __restrict__ ws,
    float* __restrict__ xc, float* __restrict__ zs) {
  __shared__ uint32_t spx[16 * 3];
  int p0 = blockIdx.x * 16;
  if (threadIdx.x < 48) {
    int pix = threadIdx.x / 3, wd = threadIdx.x % 3;
    const float* base = x + (size_t)(p0 + pix) * DM + wd * 32;
    uint32_t wv = 0;
    #pragma unroll
    for (int i = 0; i < 32; ++i) wv |= (base[i] > 0.f ? 1u : 0u) << i;
    spx[pix * 3 + wd] = wv;
  }
  __syncthreads();
  int o = threadIdx.x;
  uint32_t w0, w1, w2;
  {
    const uint32_t* wb = (const uint32_t*)(ws + OFF_WBIB) + o * 3;
    w0 = wb[0]; w1 = wb[1]; w2 = wb[2];
  }
  float bias = b_in[o], sc = s_in[o];
  int b = p0 >> 12, l0 = p0 & 4095;
  #pragma unroll
  for (int pix = 0; pix < 16; ++pix) {
    int P = (int)__popc(spx[pix * 3 + 0] ^ w0) + (int)__popc(spx[pix * 3 + 1] ^ w1) +
            (int)__popc(spx[pix * 3 + 2] ^ w2);
    float acc = bias + sc * (float)(DM - 2 * P);
    if (o < DN) xc[((size_t)(b * DN + o)) * LL + l0 + pix] = acc;
    else        zs[(size_t)(p0 + pix) * DN + (o - DN)] = siluf(acc);
  }
}

// ---------------- pack sign(xc+move0) into zero-padded bit-planes ----------------
__global__ __launch_bounds__(256) void k_pack(
    const float* __restrict__ xc, const float* __restrict__ move0,
    uint32_t* __restrict__ xb) {
  int t = blockIdx.x * 256 + threadIdx.x;
  int w2 = t & 31;
  int h = (t >> 5) & 63;
  int g = t >> 11;
  int cw = g % 6, b = g / 6;
  const float* xp = xc + ((size_t)(b * DN + cw * 32)) * LL + h * 64 + w2 * 2;
  uint32_t w0 = 0, w1 = 0;
  #pragma unroll
  for (int i = 0; i < 32; ++i) {
    float m = move0[cw * 32 + i];
    float2 v = *(const float2*)(xp + (size_t)i * LL);
    w0 |= (v.x + m > 0.f ? 1u : 0u) << i;
    w1 |= (v.y + m > 0.f ? 1u : 0u) << i;
  }
  uint32_t* plane = xb + (size_t)(b * 6 + cw) * PLANE;
  plane[(h + 1) * 66 + 1 + w2 * 2] = w0;
  plane[(h + 1) * 66 + 2 + w2 * 2] = w1;
}

// ---------------- XNOR-popcount binary 3x3 conv + RPReLU + residual + SiLU ----------------
__global__ __launch_bounds__(256) void k_conv(
    const uint32_t* __restrict__ xb, const float* __restrict__ xc,
    const uint32_t* __restrict__ wbits, const int* __restrict__ aux,
    const float* __restrict__ scf, const float* __restrict__ conv_b,
    const float* __restrict__ rp_b0, const float* __restrict__ prelu_a,
    const float* __restrict__ rp_b1, float* __restrict__ xconv) {
  int og = blockIdx.x & 3;
  int stripe = (blockIdx.x >> 2) & 15;
  int b = blockIdx.x >> 6;
  int w = threadIdx.x & 63, r = threadIdx.x >> 6;
  int h = stripe * 4 + r;

  __shared__ uint32_t swb[48 * 56];
  __shared__ int saux[48 * 8];
  __shared__ float sconst[48 * 4];
  for (int i = threadIdx.x; i < 48 * 56; i += 256) swb[i] = wbits[og * (48 * 56) + i];
  for (int i = threadIdx.x; i < 48 * 8; i += 256) saux[i] = aux[og * (48 * 8) + i];
  if (threadIdx.x < 48) {
    int o = og * 48 + threadIdx.x;
    sconst[threadIdx.x * 4 + 0] = scf[o];
    sconst[threadIdx.x * 4 + 1] = conv_b[o] + rp_b0[o];
    sconst[threadIdx.x * 4 + 2] = prelu_a[o];
    sconst[threadIdx.x * 4 + 3] = rp_b1[o];
  }

  uint32_t xw[6][9];
  const uint32_t* xpb = xb + (size_t)b * 6 * PLANE;
  #pragma unroll
  for (int cw = 0; cw < 6; ++cw) {
    const uint32_t* plane = xpb + cw * PLANE + (h + 1) * 66 + (w + 1);
    #pragma unroll
    for (int dy = 0; dy < 3; ++dy) {
      #pragma unroll
      for (int dx = 0; dx < 3; ++dx)
        xw[cw][dy * 3 + dx] = plane[(dy - 1) * 66 + (dx - 1)];
    }
  }
  bool isL = (w == 0), isR = (w == 63);
  bool isT = (h == 0), isB = (h == 63);
  const float* xcp = xc + ((size_t)(b * DN + og * 48)) * LL + h * 64 + w;
  float* xop = xconv + ((size_t)(b * DN + og * 48)) * LL + h * 64 + w;
  __syncthreads();

  #pragma unroll 1
  for (int oc = 0; oc < 48; ++oc) {
    const uint32_t* wp = &swb[oc * 56];
    int P = 0;
    #pragma unroll
    for (int cw = 0; cw < 6; ++cw) {
      int pp = 0;
      #pragma unroll
      for (int t = 0; t < 9; ++t) pp += (int)__popc(wp[cw * 9 + t] ^ xw[cw][t]);
      P += pp;
    }
    int corr = isL ? saux[oc * 8 + 0] : (isR ? saux[oc * 8 + 1] : 0);
    if (isT) {
      corr += saux[oc * 8 + 2];
      if (isL) corr -= saux[oc * 8 + 4];
      if (isR) corr -= saux[oc * 8 + 5];
    }
    if (isB) {
      corr += saux[oc * 8 + 3];
      if (isL) corr -= saux[oc * 8 + 6];
      if (isR) corr -= saux[oc * 8 + 7];
    }
    float acc = sconst[oc * 4 + 0] * (float)(1728 - 2 * P + corr);
    float t = acc + sconst[oc * 4 + 1];
    t = (t >= 0.f) ? t : sconst[oc * 4 + 2] * t;
    t += sconst[oc * 4 + 3] + *xcp;
    *xop = siluf(t);
    xcp += LL; xop += LL;
  }
}

// ---------------- build xs: LDS-tiled 4-direction expand + ballot bit-pack ----------------
// one block per (b,d) image; all global reads/writes coalesced
__global__ __launch_bounds__(256) void k_build_xs(const float* __restrict__ xconv,
                                                  float* __restrict__ xs,
                                                  uint32_t* __restrict__ pxs) {
  __shared__ float tile[64][65];
  int bd = blockIdx.x;
  int b = bd / DN, d = bd % DN;
  const float* img = xconv + (size_t)bd * LL;
  for (int i = threadIdx.x; i < LL; i += 256)
    tile[i >> 6][i & 63] = img[i];
  __syncthreads();
  int lane = threadIdx.x & 63;
  #pragma unroll
  for (int k = 0; k < 4; ++k) {
    size_t base = ((size_t)((b * KK + k) * DN + d)) * LL;
    for (int j = threadIdx.x; j < LL; j += 256) {
      float v;
      if (k == 0)      v = tile[j >> 6][j & 63];
      else if (k == 1) v = tile[j & 63][j >> 6];
      else if (k == 2) { int t2 = 4095 - j; v = tile[t2 >> 6][t2 & 63]; }
      else             { int t2 = 4095 - j; v = tile[t2 & 63][t2 >> 6]; }
      xs[base + j] = v;
      unsigned long long m = __ballot(v > 0.f);
      if (lane == 0)       pxs[(base + j) >> 5] = (uint32_t)m;
      else if (lane == 32) pxs[(base + j) >> 5] = (uint32_t)(m >> 32);
    }
  }
}

// ---------------- x_dbl via XOR-popcount ----------------
__global__ __launch_bounds__(256) void k_xdbl(
    const uint32_t* __restrict__ pxs, const float* __restrict__ ws,
    const float* __restrict__ bl, const float* __restrict__ sl,
    float* __restrict__ xdbl) {
  int bk = blockIdx.x >> 4;
  int l = ((blockIdx.x & 15) << 8) + threadIdx.x;
  int k = bk & 3;
  __shared__ uint32_t swl[RN * 6];
  __shared__ float sbias[RN], ssc[RN];
  if (threadIdx.x < RN * 6) swl[threadIdx.x] = ((const uint32_t*)(ws + OFF_WLBB))[k * RN * 6 + threadIdx.x];
  if (threadIdx.x < RN) {
    sbias[threadIdx.x] = bl[k * RN + threadIdx.x];
    ssc[threadIdx.x] = sl[k * RN + threadIdx.x];
  }
  uint32_t xb[6];
  const uint32_t* pp = pxs + (size_t)bk * 24576 + (size_t)l * 6;
  #pragma unroll
  for (int j = 0; j < 6; ++j) xb[j] = pp[j];
  __syncthreads();
  float* xo = xdbl + (size_t)bk * (RN * LL) + l;
  #pragma unroll 1
  for (int o = 0; o < RN; ++o) {
    int P = 0;
    #pragma unroll
    for (int j = 0; j < 6; ++j) P += (int)__popc(xb[j] ^ swl[o * 6 + j]);
    xo[(size_t)o * LL] = sbias[o] + ssc[o] * (float)(DN - 2 * P);
  }
}

// power ladder: a[n] = r^(n+1), 14 mults, depth 4
__device__ __forceinline__ void rpowers(float r, float* a) {
  float r2 = r * r, r3 = r2 * r, r4 = r2 * r2, r8 = r4 * r4;
  a[0] = r;       a[1] = r2;      a[2] = r3;      a[3] = r4;
  a[4] = r4 * r;  a[5] = r4 * r2; a[6] = r4 * r3; a[7] = r8;
  a[8] = r8 * r;  a[9] = r8 * r2; a[10] = r8 * r3; a[11] = r8 * r4;
  a[12] = r8 * a[4]; a[13] = r8 * a[5]; a[14] = r8 * a[6]; a[15] = r8 * r8;
}

// ---------------- scan pass A ----------------
__global__ __launch_bounds__(192) void k_scan_a(
    const float* __restrict__ xs, const float* __restrict__ xdbl,
    const float* __restrict__ ws, const float* __restrict__ bd,
    const float* __restrict__ dt_bias, const float* __restrict__ A_logs,
    float* __restrict__ hend, float* __restrict__ Ssum) {
  int c = blockIdx.x & 63;
  int bk = blockIdx.x >> 6;
  int k = bk & 3;
  int d = threadIdx.x;
  int t0 = c << 6;
  __shared__ float sdt[384];
  __shared__ float4 sB4[256];
  float* sBf = (float*)sB4;
  const float* dtbase = xdbl + (size_t)bk * (RN * LL);
  for (int i = d; i < 384; i += 192) sdt[i] = fsign(dtbase[t0 * 6 + i]);
  {
    const float4* Bp = (const float4*)(xdbl + ((size_t)bk * RN + RR) * LL);
    for (int i = d; i < 256; i += 192) {
      int n = i >> 4, j = i & 15;
      float4 v = Bp[n * 1024 + (t0 >> 2) + j];
      sBf[(4 * j + 0) * 16 + n] = v.x;
      sBf[(4 * j + 1) * 16 + n] = v.y;
      sBf[(4 * j + 2) * 16 + n] = v.z;
      sBf[(4 * j + 3) * 16 + n] = v.w;
    }
  }
  float wd[6];
  {
    const float* wdp = ws + OFF_WDB + (k * DN + d) * RR;
    #pragma unroll
    for (int r = 0; r < RR; ++r) wd[r] = wdp[r];
  }
  float biasd = bd[k * DN + d] + dt_bias[k * DN + d];
  float Araw[16];
  bool fok = true;
  {
    const float* ap = A_logs + (k * DN + d) * NN;
    #pragma unroll
    for (int n = 0; n < NN; ++n) {
      Araw[n] = -expf(ap[n]);
      fok = fok && (fabsf(Araw[n] + (float)(n + 1)) < 1e-3f);
    }
  }
  bool fastpath = (__ballot(fok) == ~0ull);
  float h[16];
  #pragma unroll
  for (int n = 0; n < NN; ++n) h[n] = 0.f;
  float S = 0.f;
  const float* up = xs + ((size_t)bk * DN + d) * LL + t0;
  __syncthreads();
  if (fastpath) {
    #pragma unroll 1
    for (int tt = 0; tt < 16; ++tt) {
      float4 u4 = *(const float4*)(up + 4 * tt);
      #pragma unroll
      for (int q = 0; q < 4; ++q) {
        int t = 4 * tt + q;
        float uv = (q == 0) ? u4.x : (q == 1) ? u4.y : (q == 2) ? u4.z : u4.w;
        float acc = biasd;
        #pragma unroll
        for (int r = 0; r < RR; ++r) acc += sdt[t * 6 + r] * wd[r];
        float dv = softplusf(acc);
        float rr = exp2f(-dv * LOG2E);
        S += dv;
        float du = dv * uv;
        float a[16];
        rpowers(rr, a);
        #pragma unroll
        for (int g = 0; g < 4; ++g) {
          float4 bv = sB4[t * 4 + g];
          h[4 * g + 0] = a[4 * g + 0] * h[4 * g + 0] + du * bv.x;
          h[4 * g + 1] = a[4 * g + 1] * h[4 * g + 1] + du * bv.y;
          h[4 * g + 2] = a[4 * g + 2] * h[4 * g + 2] + du * bv.z;
          h[4 * g + 3] = a[4 * g + 3] * h[4 * g + 3] + du * bv.w;
        }
      }
    }
  } else {
    float An[16];
    #pragma unroll
    for (int n = 0; n < NN; ++n) An[n] = Araw[n] * LOG2E;
    #pragma unroll 1
    for (int tt = 0; tt < 16; ++tt) {
      float4 u4 = *(const float4*)(up + 4 * tt);
      #pragma unroll
      for (int q = 0; q < 4; ++q) {
        int t = 4 * tt + q;
        float uv = (q == 0) ? u4.x : (q == 1) ? u4.y : (q == 2) ? u4.z : u4.w;
        float acc = biasd;
        #pragma unroll
        for (int r = 0; r < RR; ++r) acc += sdt[t * 6 + r] * wd[r];
        float dv = softplusf(acc);
        S += dv;
        float du = dv * uv;
        #pragma unroll
        for (int g = 0; g < 4; ++g) {
          float4 bv = sB4[t * 4 + g];
          float a0 = exp2f(dv * An[4 * g + 0]);
          float a1 = exp2f(dv * An[4 * g + 1]);
          float a2 = exp2f(dv * An[4 * g + 2]);
          float a3 = exp2f(dv * An[4 * g + 3]);
          h[4 * g + 0] = a0 * h[4 * g + 0] + du * bv.x;
          h[4 * g + 1] = a1 * h[4 * g + 1] + du * bv.y;
          h[4 * g + 2] = a2 * h[4 * g + 2] + du * bv.z;
          h[4 * g + 3] = a3 * h[4 * g + 3] + du * bv.w;
        }
      }
    }
  }
  float* hp = hend + (size_t)c * 49152 + (size_t)(bk * DN + d) * 16;
  #pragma unroll
  for (int n = 0; n < NN; n += 4)
    *(float4*)(hp + n) = make_float4(h[n], h[n + 1], h[n + 2], h[n + 3]);
  Ssum[c * 3072 + bk * DN + d] = S;
}

// ---------------- scan pass B ----------------
__global__ __launch_bounds__(256) void k_scan_b(
    const float* __restrict__ A_logs, const float* __restrict__ Ssum,
    float* __restrict__ hend) {
  int tid = blockIdx.x * 256 + threadIdx.x;
  int bkd = tid >> 4, n = tid & 15;
  int bk = bkd / DN, d = bkd - bk * DN;
  int k = bk & 3;
  float An2 = -expf(A_logs[(k * DN + d) * NN + n]) * LOG2E;
  float h = 0.f;
  float Sc = Ssum[bkd];
  float he = hend[tid];
  #pragma unroll 1
  for (int c = 0; c < 64; ++c) {
    float Sn = 0.f, hn = 0.f;
    if (c < 63) {
      Sn = Ssum[(c + 1) * 3072 + bkd];
      hn = hend[(size_t)(c + 1) * 49152 + tid];
    }
    hend[(size_t)c * 49152 + tid] = h;
    h = exp2f(An2 * Sc) * h + he;
    Sc = Sn; he = hn;
  }
}

// ---------------- scan pass C ----------------
__global__ __launch_bounds__(192) void k_scan_c(
    const float* __restrict__ xs, const float* __restrict__ xdbl,
    const float* __restrict__ ws, const float* __restrict__ bd,
    const float* __restrict__ dt_bias, const float* __restrict__ A_logs,
    const float* __restrict__ Ds, const float* __restrict__ h0buf,
    float* __restrict__ y) {
  int c = blockIdx.x & 63;
  int bk = blockIdx.x >> 6;
  int k = bk & 3;
  int d = threadIdx.x;
  int t0 = c << 6;
  __shared__ float sdt[384];
  __shared__ float4 sB4[256];
  __shared__ float4 sC4[256];
  float* sBf = (float*)sB4;
  float* sCf = (float*)sC4;
  const float* dtbase = xdbl + (size_t)bk * (RN * LL);
  for (int i = d; i < 384; i += 192) sdt[i] = fsign(dtbase[t0 * 6 + i]);
  {
    const float4* Bp = (const float4*)(xdbl + ((size_t)bk * RN + RR) * LL);
    const float4* Cp = (const float4*)(xdbl + ((size_t)bk * RN + RR + NN) * LL);
    for (int i = d; i < 256; i += 192) {
      int n = i >> 4, j = i & 15;
      float4 v = Bp[n * 1024 + (t0 >> 2) + j];
      sBf[(4 * j + 0) * 16 + n] = v.x;
      sBf[(4 * j + 1) * 16 + n] = v.y;
      sBf[(4 * j + 2) * 16 + n] = v.z;
      sBf[(4 * j + 3) * 16 + n] = v.w;
      float4 w = Cp[n * 1024 + (t0 >> 2) + j];
      sCf[(4 * j + 0) * 16 + n] = w.x;
      sCf[(4 * j + 1) * 16 + n] = w.y;
      sCf[(4 * j + 2) * 16 + n] = w.z;
      sCf[(4 * j + 3) * 16 + n] = w.w;
    }
  }
  float wd[6];
  {
    const float* wdp = ws + OFF_WDB + (k * DN + d) * RR;
    #pragma unroll
    for (int r = 0; r < RR; ++r) wd[r] = wdp[r];
  }
  float biasd = bd[k * DN + d] + dt_bias[k * DN + d];
  float Dd = Ds[k * DN + d];
  float Araw[16];
  bool fok = true;
  {
    const float* ap = A_logs + (k * DN + d) * NN;
    #pragma unroll
    for (int n = 0; n < NN; ++n) {
      Araw[n] = -expf(ap[n]);
      fok = fok && (fabsf(Araw[n] + (float)(n + 1)) < 1e-3f);
    }
  }
  bool fastpath = (__ballot(fok) == ~0ull);
  float h[16];
  {
    const float* hp = h0buf + (size_t)c * 49152 + (size_t)(bk * DN + d) * 16;
    #pragma unroll
    for (int n = 0; n < NN; n += 4) {
      float4 v = *(const float4*)(hp + n);
      h[n] = v.x; h[n + 1] = v.y; h[n + 2] = v.z; h[n + 3] = v.w;
    }
  }
  const float* up = xs + ((size_t)bk * DN + d) * LL + t0;
  float* yb = y + (size_t)(bk >> 2) * (LL * DN);
  __syncthreads();
  if (fastpath) {
    #pragma unroll 1
    for (int tt = 0; tt < 16; ++tt) {
      float4 u4 = *(const float4*)(up + 4 * tt);
      #pragma unroll
      for (int q = 0; q < 4; ++q) {
        int t = 4 * tt + q;
        float uv = (q == 0) ? u4.x : (q == 1) ? u4.y : (q == 2) ? u4.z : u4.w;
        float acc = biasd;
        #pragma unroll
        for (int r = 0; r < RR; ++r) acc += sdt[t * 6 + r] * wd[r];
        float dv = softplusf(acc);
        float rr = exp2f(-dv * LOG2E);
        float du = dv * uv;
        float yv = Dd * uv;
        float a[16];
        rpowers(rr, a);
        #pragma unroll
        for (int g = 0; g < 4; ++g) {
          float4 bv = sB4[t * 4 + g];
          float4 cv = sC4[t * 4 + g];
          h[4 * g + 0] = a[4 * g + 0] * h[4 * g + 0] + du * bv.x;
          h[4 * g + 1] = a[4 * g + 1] * h[4 * g + 1] + du * bv.y;
          h[4 * g + 2] = a[4 * g + 2] * h[4 * g + 2] + du * bv.z;
          h[4 * g + 3] = a[4 * g + 3] * h[4 * g + 3] + du * bv.w;
          yv += cv.x * h[4 * g + 0];
          yv += cv.y * h[4 * g + 1];
          yv += cv.z * h[4 * g + 2];
          yv += cv.w * h[4 * g + 3];
        }
        int ta = t0 + t, l;
        if (k == 0)      l = ta;
        else if (k == 1) l = ((ta & 63) << 6) | (ta >> 6);
        else if (k == 2) l = 4095 - ta;
        else { int t2 = 4095 - ta; l = ((t2 & 63) << 6) | (t2 >> 6); }
        atomicAdd(&yb[(size_t)l * DN + d], yv);
      }
    }
  } else {
    float An[16];
    #pragma unroll
    for (int n = 0; n < NN; ++n) An[n] = Araw[n] * LOG2E;
    #pragma unroll 1
    for (int tt = 0; tt < 16; ++tt) {
      float4 u4 = *(const float4*)(up + 4 * tt);
      #pragma unroll
      for (int q = 0; q < 4; ++q) {
        int t = 4 * tt + q;
        float uv = (q == 0) ? u4.x : (q == 1) ? u4.y : (q == 2) ? u4.z : u4.w;
        float acc = biasd;
        #pragma unroll
        for (int r = 0; r < RR; ++r) acc += sdt[t * 6 + r] * wd[r];
        float dv = softplusf(acc);
        float du = dv * uv;
        float yv = Dd * uv;
        #pragma unroll
        for (int g = 0; g < 4; ++g) {
          float4 bv = sB4[t * 4 + g];
          float4 cv = sC4[t * 4 + g];
          float a0 = exp2f(dv * An[4 * g + 0]);
          float a1 = exp2f(dv * An[4 * g + 1]);
          float a2 = exp2f(dv * An[4 * g + 2]);
          float a3 = exp2f(dv * An[4 * g + 3]);
          h[4 * g + 0] = a0 * h[4 * g + 0] + du * bv.x;
          h[4 * g + 1] = a1 * h[4 * g + 1] + du * bv.y;
          h[4 * g + 2] = a2 * h[4 * g + 2] + du * bv.z;
          h[4 * g + 3] = a3 * h[4 * g + 3] + du * bv.w;
          yv += cv.x * h[4 * g + 0];
          yv += cv.y * h[4 * g + 1];
          yv += cv.z * h[4 * g + 2];
          yv += cv.w * h[4 * g + 3];
        }
        int ta = t0 + t, l;
        if (k == 0)      l = ta;
        else if (k == 1) l = ((ta & 63) << 6) | (ta >> 6);
        else if (k == 2) l = 4095 - ta;
        else { int t2 = 4095 - ta; l = ((t2 & 63) << 6) | (t2 >> 6); }
        atomicAdd(&yb[(size_t)l * DN + d], yv);
      }
    }
  }
}

// ---------------- LayerNorm over Dn + * silu(z) -> packed sign bits ----------------
__global__ __launch_bounds__(256) void k_ln(
    const float* __restrict__ y, const float* __restrict__ zs,
    const float* __restrict__ ln_w, const float* __restrict__ ln_b,
    uint32_t* __restrict__ ybits) {
  __shared__ float ty[64 * 193];
  __shared__ float ps[256];
  __shared__ float smu[64], srs[64];
  __shared__ float slw[DN], slb[DN];
  int b = blockIdx.x >> 6;
  int l0 = (blockIdx.x & 63) << 6;
  const float* yp = y + (size_t)(b * LL + l0) * DN;
  if (threadIdx.x < DN) {
    slw[threadIdx.x] = ln_w[threadIdx.x];
    slb[threadIdx.x] = ln_b[threadIdx.x];
  }
  {
    int lc = threadIdx.x / DN, d2 = threadIdx.x - lc * DN;
    for (int i = threadIdx.x; i < 64 * DN; i += 256) {
      ty[lc * 193 + d2] = yp[i];
      d2 += 256;
      if (d2 >= DN) { d2 -= DN; lc += 1; if (d2 >= DN) { d2 -= DN; lc += 1; } }
    }
  }
  __syncthreads();
  int lc = threadIdx.x & 63, part = threadIdx.x >> 6;
  float s = 0.f;
  for (int d = part * 48; d < part * 48 + 48; ++d) s += ty[lc * 193 + d];
  ps[threadIdx.x] = s;
  __syncthreads();
  if (threadIdx.x < 64)
    smu[threadIdx.x] = (ps[threadIdx.x] + ps[threadIdx.x + 64] +
                        ps[threadIdx.x + 128] + ps[threadIdx.x + 192]) / (float)DN;
  __syncthreads();
  float mu = smu[lc];
  float q = 0.f;
  for (int d = part * 48; d < part * 48 + 48; ++d) {
    float v = ty[lc * 193 + d] - mu; q += v * v;
  }
  ps[threadIdx.x] = q;
  __syncthreads();
  if (threadIdx.x < 64) {
    float var = (ps[threadIdx.x] + ps[threadIdx.x + 64] +
                 ps[threadIdx.x + 128] + ps[threadIdx.x + 192]) / (float)DN;
    srs[threadIdx.x] = rsqrtf(var + 1e-5f);
  }
  __syncthreads();
  for (int item = threadIdx.x; item < 64 * 6; item += 256) {
    int lc2 = item / 6, wd = item % 6;
    float mu2 = smu[lc2], rs2 = srs[lc2];
    const float* zb = zs + (size_t)(b * LL + l0 + lc2) * DN + wd * 32;
    uint32_t wv = 0;
    #pragma unroll
    for (int i = 0; i < 32; ++i) {
      int d = wd * 32 + i;
      float ln = (ty[lc2 * 193 + d] - mu2) * rs2 * slw[d] + slb[d];
      wv |= ((ln * zb[i] > 0.f) ? 1u : 0u) << i;
    }
    ybits[(size_t)(b * LL + l0 + lc2) * 6 + wd] = wv;
  }
}

// ---------------- output bilinear via XOR-popcount ----------------
__global__ __launch_bounds__(256) void k_out(
    const uint32_t* __restrict__ ybits, const float* __restrict__ ws,
    const float* __restrict__ b_out, const float* __restrict__ s_out,
    float* __restrict__ out) {
  __shared__ uint32_t sy[64 * 6];
  __shared__ uint32_t swo[96 * 6];
  __shared__ float sb[96], ssc[96];
  int p0 = blockIdx.x * 64;
  for (int i = threadIdx.x; i < 64 * 6; i += 256) sy[i] = ybits[(size_t)p0 * 6 + i];
  for (int i = threadIdx.x; i < 96 * 6; i += 256) swo[i] = ((const uint32_t*)(ws + OFF_WOUTB))[i];
  if (threadIdx.x < 96) {
    sb[threadIdx.x] = b_out[threadIdx.x];
    ssc[threadIdx.x] = s_out[threadIdx.x];
  }
  __syncthreads();
  for (int oi = threadIdx.x; oi < 64 * DM; oi += 256) {
    int pr = oi / DM, m = oi % DM;
    int P = 0;
    #pragma unroll
    for (int j = 0; j < 6; ++j) P += (int)__popc(sy[pr * 6 + j] ^ swo[m * 6 + j]);
    out[(size_t)(p0 + pr) * DM + m] = sb[m] + ssc[m] * (float)(DN - 2 * P);
  }
}

extern "C" void kernel_launch(void* const* d_in, const int* in_sizes, int n_in,
                              void* d_out, int out_size, void* d_ws, size_t ws_size,
                              hipStream_t stream) {
  const float* x       = (const float*)d_in[0];
  const float* W_in    = (const float*)d_in[1];
  const float* b_in    = (const float*)d_in[2];
  const float* s_in    = (const float*)d_in[3];
  const float* move0_b = (const float*)d_in[4];
  const float* conv_W  = (const float*)d_in[5];
  const float* conv_b  = (const float*)d_in[6];
  const float* rp_b0   = (const float*)d_in[7];
  const float* prelu_a = (const float*)d_in[8];
  const float* rp_b1   = (const float*)d_in[9];
  const float* Wl      = (const float*)d_in[10];
  const float* bl      = (const float*)d_in[11];
  const float* sl      = (const float*)d_in[12];
  const float* Wd      = (const float*)d_in[13];
  const float* bd      = (const float*)d_in[14];
  const float* sd      = (const float*)d_in[15];
  const float* dt_bias = (const float*)d_in[16];
  const float* A_logs  = (const float*)d_in[17];
  const float* Ds      = (const float*)d_in[18];
  const float* ln_w    = (const float*)d_in[19];
  const float* ln_b    = (const float*)d_in[20];
  const float* W_out   = (const float*)d_in[21];
  const float* b_out   = (const float*)d_in[22];
  const float* s_out   = (const float*)d_in[23];
  float* ws  = (float*)d_ws;
  float* out = (float*)d_out;

  hipLaunchKernelGGL(k_prep, dim3(1592), dim3(64), 0, stream,
                     W_in, s_in, W_out, s_out, Wl, sl, Wd, sd, conv_W, ws);
  hipLaunchKernelGGL(k_bilin_in, dim3(1024), dim3(384), 0, stream,
                     x, b_in, s_in, ws, ws + OFF_XC, ws + OFF_ZS);
  hipMemsetAsync((void*)(ws + OFF_XBP), 0, (size_t)(4 * 6 * PLANE) * 4, stream);
  hipLaunchKernelGGL(k_pack, dim3(192), dim3(256), 0, stream,
                     ws + OFF_XC, move0_b, (uint32_t*)(ws + OFF_XBP));
  hipLaunchKernelGGL(k_conv, dim3(256), dim3(256), 0, stream,
                     (const uint32_t*)(ws + OFF_XBP), ws + OFF_XC,
                     (const uint32_t*)(ws + OFF_WCS), (const int*)(ws + OFF_WAUX),
                     ws + OFF_WSC, conv_b, rp_b0, prelu_a, rp_b1,
                     ws + OFF_XCONV);
  hipLaunchKernelGGL(k_build_xs, dim3(768), dim3(256), 0, stream,
                     ws + OFF_XCONV, ws + OFF_XS, (uint32_t*)(ws + OFF_PXS));
  hipLaunchKernelGGL(k_xdbl, dim3(256), dim3(256), 0, stream,
                     (const uint32_t*)(ws + OFF_PXS), ws, bl, sl, ws + OFF_XDBL);
  hipLaunchKernelGGL(k_scan_a, dim3(1024), dim3(192), 0, stream,
                     ws + OFF_XS, ws + OFF_XDBL, ws, bd, dt_bias, A_logs,
                     ws + OFF_HEND, ws + OFF_SSUM);
  hipLaunchKernelGGL(k_scan_b, dim3(192), dim3(256), 0, stream,
                     A_logs, ws + OFF_SSUM, ws + OFF_HEND);
  hipMemsetAsync((void*)(ws + OFF_XC), 0, (size_t)3145728 * sizeof(float), stream);
  hipLaunchKernelGGL(k_scan_c, dim3(1024), dim3(192), 0, stream,
                     ws + OFF_XS, ws + OFF_XDBL, ws, bd, dt_bias, A_logs, Ds,
                     ws + OFF_HEND, ws + OFF_XC);
  hipLaunchKernelGGL(k_ln, dim3(256), dim3(256), 0, stream,
                     ws + OFF_XC, ws + OFF_ZS, ln_w, ln_b, (uint32_t*)(ws + OFF_YB));
  hipLaunchKernelGGL(k_out, dim3(256), dim3(256), 0, stream,
                     (const uint32_t*)(ws + OFF_YB), ws, b_out, s_out, out);
}

// Round 7
// 341.774 us; speedup vs baseline: 6.0223x; 1.0324x over previous
//
#include <hip/hip_runtime.h>
#include <math.h>
#include <stdint.h>

// Problem constants
#define BB 4
#define HH 64
#define WW2 64
#define DM 96
#define DN 192
#define KK 4
#define NN 16
#define RR 6
#define LL 4096
#define RN 38   // R + 2N

#define LOG2E 1.4426950408889634f
#define LN2   0.6931471805599453f

// Workspace layout (4-byte units). Peak = 24,923,456 floats = 99.69 MB.
#define OFF_WDB      0           // u32[768] packed Wd sign bits + float[768] sd at +768
#define OFF_WCS      4608        // u32[192*56] packed conv weights
#define OFF_WAUX     15360       // int[192*8] conv border corrections
#define OFF_WSC      16896       // float[192] conv scale
#define OFF_WBIB     17088       // u32[384*3] packed W_in sign bits
#define OFF_WOUTB    18240       // u32[96*6] packed W_out sign bits
#define OFF_WLBB     18816       // u32[152*6] packed Wl sign bits
// shared scratch pool (lifetime-disjoint): 393216 words @ 19728
#define OFF_XBP      19728       // u32[4*6*4356] conv input bit planes
#define OFF_PXS      19728       // u32[16*24576] packed sign(xs) flat
#define OFF_SSUM     19728       // float[64*3072] chunk delta sums
#define OFF_YB       19728       // u32[16384*6] packed sign(ln*silu z)
#define OFF_XC       412992      // float[3145728] xp (B,Dn,L); reused as y accum [b][L][d]
#define OFF_ZS       3558720     // float[3145728] silu(z) (B,L,Dn)
#define OFF_XCONV    6704448     // float[3145728] conv out (B,Dn,L); reused as hend/h0
#define OFF_XS       9850176     // float[12582912] 4-direction scan input
#define OFF_XDBL     22433088    // float[16*38*4096] x_dbl (B,K,38,L)
#define OFF_HEND     OFF_XCONV

#define PLANE 4356   // 66*66

__device__ __forceinline__ float fsign(float v) {
  return (v > 0.f) ? 1.f : ((v < 0.f) ? -1.f : 0.f);
}
__device__ __forceinline__ float softplusf(float v) {
  return fmaxf(v, 0.f) + LN2 * log2f(1.f + exp2f(-fabsf(v) * LOG2E));
}
__device__ __forceinline__ float siluf(float v) {
  return v / (1.f + expf(-v));
}
__device__ __forceinline__ float waveAllSum(float s) {
  #pragma unroll
  for (int off = 32; off; off >>= 1) s += __shfl_xor(s, off, 64);
  return s;
}

// ---------------- prep: pack all sign weights ----------------
__global__ __launch_bounds__(64) void k_prep(
    const float* __restrict__ W_in, const float* __restrict__ s_in,
    const float* __restrict__ W_out, const float* __restrict__ s_out,
    const float* __restrict__ Wl, const float* __restrict__ sl,
    const float* __restrict__ Wd, const float* __restrict__ sd,
    const float* __restrict__ convW, float* __restrict__ ws) {
  int r = blockIdx.x, lane = threadIdx.x;
  if (r < 384) {                 // W_in rows (len 96) -> 3 words
    const float* row = W_in + r * DM;
    float s = 0.f;
    for (int c = lane; c < DM; c += 64) s += row[c];
    s = waveAllSum(s);
    float mean = s / (float)DM;
    if (lane < 3) {
      uint32_t wv = 0;
      #pragma unroll
      for (int i = 0; i < 32; ++i) wv |= (row[lane * 32 + i] - mean > 0.f ? 1u : 0u) << i;
      ((uint32_t*)(ws + OFF_WBIB))[r * 3 + lane] = wv;
    }
  } else if (r < 480) {          // W_out rows (len 192) -> 6 words
    int m = r - 384;
    const float* row = W_out + m * DN;
    float s = 0.f;
    for (int c = lane; c < DN; c += 64) s += row[c];
    s = waveAllSum(s);
    float mean = s / (float)DN;
    if (lane < 6) {
      uint32_t wv = 0;
      #pragma unroll
      for (int i = 0; i < 32; ++i) wv |= (row[lane * 32 + i] - mean > 0.f ? 1u : 0u) << i;
      ((uint32_t*)(ws + OFF_WOUTB))[m * 6 + lane] = wv;
    }
  } else if (r < 632) {          // Wl rows (len 192) -> 6 words
    int idx = r - 480;
    const float* row = Wl + idx * DN;
    float s = 0.f;
    for (int c = lane; c < DN; c += 64) s += row[c];
    s = waveAllSum(s);
    float mean = s / (float)DN;
    if (lane < 6) {
      uint32_t wv = 0;
      #pragma unroll
      for (int i = 0; i < 32; ++i) wv |= (row[lane * 32 + i] - mean > 0.f ? 1u : 0u) << i;
      ((uint32_t*)(ws + OFF_WLBB))[idx * 6 + lane] = wv;
    }
  } else if (r < 1400) {         // Wd rows (len 6) -> 6-bit mask + sd magnitude
    int idx = r - 632;
    const float* row = Wd + idx * RR;
    float s = (lane < RR) ? row[lane] : 0.f;
    s = waveAllSum(s);
    float mean = s / (float)RR;
    unsigned long long mb = __ballot((lane < RR) && (row[lane] - mean > 0.f));
    if (lane == 0) {
      ((uint32_t*)(ws + OFF_WDB))[idx] = (uint32_t)mb & 0x3Fu;
      (ws + OFF_WDB)[768 + idx] = sd[idx];
    }
  } else {                       // conv channel o
    int o = r - 1400;
    const float* row = convW + o * 1728;
    float s = 0.f;
    for (int j = lane; j < 1728; j += 64) s += fabsf(row[j]);
    s = waveAllSum(s);
    float sc = s / 1728.f;
    uint32_t* wb = (uint32_t*)(ws + OFF_WCS);
    int* aux = (int*)(ws + OFF_WAUX);
    float* scf = ws + OFF_WSC;
    uint32_t word = 0;
    if (lane < 54) {
      int cw = lane / 9, tap = lane % 9;
      #pragma unroll
      for (int i = 0; i < 32; ++i)
        word |= (row[(cw * 32 + i) * 9 + tap] > 0.f ? 1u : 0u) << i;
      wb[o * 56 + lane] = word;
    } else if (lane < 56) {
      wb[o * 56 + lane] = 0u;
    }
    int pc = (lane < 54) ? 2 * (int)__popc(word) - 32 : 0;
    int tapid = lane % 9;
    int wst = 0;
    #pragma unroll
    for (int cw = 0; cw < 6; ++cw) wst += __shfl(pc, cw * 9 + tapid, 64);
    int w_t[9];
    #pragma unroll
    for (int t9 = 0; t9 < 9; ++t9) w_t[t9] = __shfl(wst, t9, 64);
    if (lane == 0) {
      aux[o * 8 + 0] = w_t[0] + w_t[3] + w_t[6];
      aux[o * 8 + 1] = w_t[2] + w_t[5] + w_t[8];
      aux[o * 8 + 2] = w_t[0] + w_t[1] + w_t[2];
      aux[o * 8 + 3] = w_t[6] + w_t[7] + w_t[8];
      aux[o * 8 + 4] = w_t[0];
      aux[o * 8 + 5] = w_t[2];
      aux[o * 8 + 6] = w_t[6];
      aux[o * 8 + 7] = w_t[8];
      scf[o] = sc;
    }
  }
}

// ---------------- input bilinear via XOR-popcount, LDS-transposed coalesced stores ----------------
__global__ __launch_bounds__(384) void k_bilin_in(
    const float* __restrict__ x, const float* __restrict__ b_in,
    const float* __restrict__ s_in, const float* __restrict__ ws,
    float* __restrict__ xc, float* __restrict__ zs) {
  __shared__ uint32_t spx[16 * 3];
  __shared__ float sxz[384 * 17];
  int p0 = blockIdx.x * 16;
  if (threadIdx.x < 48) {
    int pix = threadIdx.x / 3, wd = threadIdx.x % 3;
    const float* base = x + (size_t)(p0 + pix) * DM + wd * 32;
    uint32_t wv = 0;
    #pragma unroll
    for (int i = 0; i < 32; ++i) wv |= (base[i] > 0.f ? 1u : 0u) << i;
    spx[pix * 3 + wd] = wv;
  }
  __syncthreads();
  int o = threadIdx.x;
  uint32_t w0, w1, w2;
  {
    const uint32_t* wb = (const uint32_t*)(ws + OFF_WBIB) + o * 3;
    w0 = wb[0]; w1 = wb[1]; w2 = wb[2];
  }
  float bias = b_in[o], sc = s_in[o];
  #pragma unroll
  for (int pix = 0; pix < 16; ++pix) {
    int P = (int)__popc(spx[pix * 3 + 0] ^ w0) + (int)__popc(spx[pix * 3 + 1] ^ w1) +
            (int)__popc(spx[pix * 3 + 2] ^ w2);
    sxz[o * 17 + pix] = bias + sc * (float)(DM - 2 * P);
  }
  __syncthreads();
  int b = p0 >> 12, l0 = p0 & 4095;
  // xc part: [b][d][l], 16 consecutive l per d -> coalesced 64B segments
  for (int f = threadIdx.x; f < DN * 16; f += 384) {
    int od = f >> 4, pix = f & 15;
    xc[((size_t)(b * DN + od)) * LL + l0 + pix] = sxz[od * 17 + pix];
  }
  // z part: [p][dz] linear -> coalesced
  for (int f = threadIdx.x; f < DN * 16; f += 384) {
    int pix = f / DN, oz = f - pix * DN;
    zs[(size_t)(p0 + pix) * DN + oz] = siluf(sxz[(DN + oz) * 17 + pix]);
  }
}

// ---------------- pack sign(xc+move0) into zero-padded bit-planes ----------------
__global__ __launch_bounds__(256) void k_pack(
    const float* __restrict__ xc, const float* __restrict__ move0,
    uint32_t* __restrict__ xb) {
  int t = blockIdx.x * 256 + threadIdx.x;
  int w2 = t & 31;
  int h = (t >> 5) & 63;
  int g = t >> 11;
  int cw = g % 6, b = g / 6;
  const float* xp = xc + ((size_t)(b * DN + cw * 32)) * LL + h * 64 + w2 * 2;
  uint32_t w0 = 0, w1 = 0;
  #pragma unroll
  for (int i = 0; i < 32; ++i) {
    float m = move0[cw * 32 + i];
    float2 v = *(const float2*)(xp + (size_t)i * LL);
    w0 |= (v.x + m > 0.f ? 1u : 0u) << i;
    w1 |= (v.y + m > 0.f ? 1u : 0u) << i;
  }
  uint32_t* plane = xb + (size_t)(b * 6 + cw) * PLANE;
  plane[(h + 1) * 66 + 1 + w2 * 2] = w0;
  plane[(h + 1) * 66 + 2 + w2 * 2] = w1;
}

// ---------------- XNOR-popcount binary 3x3 conv + RPReLU + residual + SiLU ----------------
__global__ __launch_bounds__(256) void k_conv(
    const uint32_t* __restrict__ xb, const float* __restrict__ xc,
    const uint32_t* __restrict__ wbits, const int* __restrict__ aux,
    const float* __restrict__ scf, const float* __restrict__ conv_b,
    const float* __restrict__ rp_b0, const float* __restrict__ prelu_a,
    const float* __restrict__ rp_b1, float* __restrict__ xconv) {
  int og = blockIdx.x & 3;
  int stripe = (blockIdx.x >> 2) & 15;
  int b = blockIdx.x >> 6;
  int w = threadIdx.x & 63, r = threadIdx.x >> 6;
  int h = stripe * 4 + r;

  __shared__ uint32_t swb[48 * 56];
  __shared__ int saux[48 * 8];
  __shared__ float sconst[48 * 4];
  for (int i = threadIdx.x; i < 48 * 56; i += 256) swb[i] = wbits[og * (48 * 56) + i];
  for (int i = threadIdx.x; i < 48 * 8; i += 256) saux[i] = aux[og * (48 * 8) + i];
  if (threadIdx.x < 48) {
    int o = og * 48 + threadIdx.x;
    sconst[threadIdx.x * 4 + 0] = scf[o];
    sconst[threadIdx.x * 4 + 1] = conv_b[o] + rp_b0[o];
    sconst[threadIdx.x * 4 + 2] = prelu_a[o];
    sconst[threadIdx.x * 4 + 3] = rp_b1[o];
  }

  uint32_t xw[6][9];
  const uint32_t* xpb = xb + (size_t)b * 6 * PLANE;
  #pragma unroll
  for (int cw = 0; cw < 6; ++cw) {
    const uint32_t* plane = xpb + cw * PLANE + (h + 1) * 66 + (w + 1);
    #pragma unroll
    for (int dy = 0; dy < 3; ++dy) {
      #pragma unroll
      for (int dx = 0; dx < 3; ++dx)
        xw[cw][dy * 3 + dx] = plane[(dy - 1) * 66 + (dx - 1)];
    }
  }
  bool isL = (w == 0), isR = (w == 63);
  bool isT = (h == 0), isB = (h == 63);
  const float* xcp = xc + ((size_t)(b * DN + og * 48)) * LL + h * 64 + w;
  float* xop = xconv + ((size_t)(b * DN + og * 48)) * LL + h * 64 + w;
  __syncthreads();

  #pragma unroll 1
  for (int oc = 0; oc < 48; ++oc) {
    const uint32_t* wp = &swb[oc * 56];
    int P = 0;
    #pragma unroll
    for (int cw = 0; cw < 6; ++cw) {
      int pp = 0;
      #pragma unroll
      for (int t = 0; t < 9; ++t) pp += (int)__popc(wp[cw * 9 + t] ^ xw[cw][t]);
      P += pp;
    }
    int corr = isL ? saux[oc * 8 + 0] : (isR ? saux[oc * 8 + 1] : 0);
    if (isT) {
      corr += saux[oc * 8 + 2];
      if (isL) corr -= saux[oc * 8 + 4];
      if (isR) corr -= saux[oc * 8 + 5];
    }
    if (isB) {
      corr += saux[oc * 8 + 3];
      if (isL) corr -= saux[oc * 8 + 6];
      if (isR) corr -= saux[oc * 8 + 7];
    }
    float acc = sconst[oc * 4 + 0] * (float)(1728 - 2 * P + corr);
    float t = acc + sconst[oc * 4 + 1];
    t = (t >= 0.f) ? t : sconst[oc * 4 + 2] * t;
    t += sconst[oc * 4 + 3] + *xcp;
    *xop = siluf(t);
    xcp += LL; xop += LL;
  }
}

// ---------------- build xs: LDS-tiled 4-direction expand + ballot bit-pack ----------------
__global__ __launch_bounds__(256) void k_build_xs(const float* __restrict__ xconv,
                                                  float* __restrict__ xs,
                                                  uint32_t* __restrict__ pxs) {
  __shared__ float tile[64][65];
  int bd = blockIdx.x;
  int b = bd / DN, d = bd % DN;
  const float* img = xconv + (size_t)bd * LL;
  for (int i = threadIdx.x; i < LL; i += 256)
    tile[i >> 6][i & 63] = img[i];
  __syncthreads();
  int lane = threadIdx.x & 63;
  #pragma unroll
  for (int k = 0; k < 4; ++k) {
    size_t base = ((size_t)((b * KK + k) * DN + d)) * LL;
    for (int j = threadIdx.x; j < LL; j += 256) {
      float v;
      if (k == 0)      v = tile[j >> 6][j & 63];
      else if (k == 1) v = tile[j & 63][j >> 6];
      else if (k == 2) { int t2 = 4095 - j; v = tile[t2 >> 6][t2 & 63]; }
      else             { int t2 = 4095 - j; v = tile[t2 & 63][t2 >> 6]; }
      xs[base + j] = v;
      unsigned long long m = __ballot(v > 0.f);
      if (lane == 0)       pxs[(base + j) >> 5] = (uint32_t)m;
      else if (lane == 32) pxs[(base + j) >> 5] = (uint32_t)(m >> 32);
    }
  }
}

// ---------------- x_dbl via XOR-popcount ----------------
__global__ __launch_bounds__(256) void k_xdbl(
    const uint32_t* __restrict__ pxs, const float* __restrict__ ws,
    const float* __restrict__ bl, const float* __restrict__ sl,
    float* __restrict__ xdbl) {
  int bk = blockIdx.x >> 4;
  int l = ((blockIdx.x & 15) << 8) + threadIdx.x;
  int k = bk & 3;
  __shared__ uint32_t swl[RN * 6];
  __shared__ float sbias[RN], ssc[RN];
  if (threadIdx.x < RN * 6) swl[threadIdx.x] = ((const uint32_t*)(ws + OFF_WLBB))[k * RN * 6 + threadIdx.x];
  if (threadIdx.x < RN) {
    sbias[threadIdx.x] = bl[k * RN + threadIdx.x];
    ssc[threadIdx.x] = sl[k * RN + threadIdx.x];
  }
  uint32_t xb[6];
  const uint32_t* pp = pxs + (size_t)bk * 24576 + (size_t)l * 6;
  #pragma unroll
  for (int j = 0; j < 6; ++j) xb[j] = pp[j];
  __syncthreads();
  float* xo = xdbl + (size_t)bk * (RN * LL) + l;
  #pragma unroll 1
  for (int o = 0; o < RN; ++o) {
    int P = 0;
    #pragma unroll
    for (int j = 0; j < 6; ++j) P += (int)__popc(xb[j] ^ swl[o * 6 + j]);
    xo[(size_t)o * LL] = sbias[o] + ssc[o] * (float)(DN - 2 * P);
  }
}

// power ladder: a[n] = r^(n+1), 14 mults, depth 4
__device__ __forceinline__ void rpowers(float r, float* a) {
  float r2 = r * r, r3 = r2 * r, r4 = r2 * r2, r8 = r4 * r4;
  a[0] = r;       a[1] = r2;      a[2] = r3;      a[3] = r4;
  a[4] = r4 * r;  a[5] = r4 * r2; a[6] = r4 * r3; a[7] = r8;
  a[8] = r8 * r;  a[9] = r8 * r2; a[10] = r8 * r3; a[11] = r8 * r4;
  a[12] = r8 * a[4]; a[13] = r8 * a[5]; a[14] = r8 * a[6]; a[15] = r8 * r8;
}

// ---------------- scan pass A ----------------
__global__ __launch_bounds__(192) void k_scan_a(
    const float* __restrict__ xs, const float* __restrict__ xdbl,
    const float* __restrict__ ws, const float* __restrict__ bd,
    const float* __restrict__ dt_bias, const float* __restrict__ A_logs,
    float* __restrict__ hend, float* __restrict__ Ssum) {
  int c = blockIdx.x & 63;
  int bk = blockIdx.x >> 6;
  int k = bk & 3;
  int d = threadIdx.x;
  int t0 = c << 6;
  __shared__ uint32_t sdtm[64];
  __shared__ float4 sB4[256];
  float* sBf = (float*)sB4;
  const float* dtbase = xdbl + (size_t)bk * (RN * LL);
  if (d < 64) {   // pack 6 sign bits per step
    const float2* p2 = (const float2*)(dtbase + t0 * 6 + d * 6);
    float2 a = p2[0], bb = p2[1], cc = p2[2];
    uint32_t m = (a.x > 0.f ? 1u : 0u) | (a.y > 0.f ? 2u : 0u) |
                 (bb.x > 0.f ? 4u : 0u) | (bb.y > 0.f ? 8u : 0u) |
                 (cc.x > 0.f ? 16u : 0u) | (cc.y > 0.f ? 32u : 0u);
    sdtm[d] = m;
  }
  {
    const float4* Bp = (const float4*)(xdbl + ((size_t)bk * RN + RR) * LL);
    for (int i = d; i < 256; i += 192) {
      int n = i >> 4, j = i & 15;
      float4 v = Bp[n * 1024 + (t0 >> 2) + j];
      sBf[(4 * j + 0) * 16 + n] = v.x;
      sBf[(4 * j + 1) * 16 + n] = v.y;
      sBf[(4 * j + 2) * 16 + n] = v.z;
      sBf[(4 * j + 3) * 16 + n] = v.w;
    }
  }
  uint32_t w6 = ((const uint32_t*)(ws + OFF_WDB))[k * DN + d];
  float sdv = (ws + OFF_WDB)[768 + k * DN + d];
  float biasd = bd[k * DN + d] + dt_bias[k * DN + d];
  float Araw[16];
  bool fok = true;
  {
    const float* ap = A_logs + (k * DN + d) * NN;
    #pragma unroll
    for (int n = 0; n < NN; ++n) {
      Araw[n] = -expf(ap[n]);
      fok = fok && (fabsf(Araw[n] + (float)(n + 1)) < 1e-3f);
    }
  }
  bool fastpath = (__ballot(fok) == ~0ull);
  float h[16];
  #pragma unroll
  for (int n = 0; n < NN; ++n) h[n] = 0.f;
  float S = 0.f;
  const float* up = xs + ((size_t)bk * DN + d) * LL + t0;
  __syncthreads();
  if (fastpath) {
    #pragma unroll 1
    for (int tt = 0; tt < 16; ++tt) {
      float4 u4 = *(const float4*)(up + 4 * tt);
      #pragma unroll
      for (int q = 0; q < 4; ++q) {
        int t = 4 * tt + q;
        float uv = (q == 0) ? u4.x : (q == 1) ? u4.y : (q == 2) ? u4.z : u4.w;
        int pc = (int)__popc(sdtm[t] ^ w6);
        float dv = softplusf(biasd + sdv * (float)(RR - 2 * pc));
        float rr = exp2f(-dv * LOG2E);
        S += dv;
        float du = dv * uv;
        float a[16];
        rpowers(rr, a);
        #pragma unroll
        for (int g = 0; g < 4; ++g) {
          float4 bv = sB4[t * 4 + g];
          h[4 * g + 0] = a[4 * g + 0] * h[4 * g + 0] + du * bv.x;
          h[4 * g + 1] = a[4 * g + 1] * h[4 * g + 1] + du * bv.y;
          h[4 * g + 2] = a[4 * g + 2] * h[4 * g + 2] + du * bv.z;
          h[4 * g + 3] = a[4 * g + 3] * h[4 * g + 3] + du * bv.w;
        }
      }
    }
  } else {
    float An[16];
    #pragma unroll
    for (int n = 0; n < NN; ++n) An[n] = Araw[n] * LOG2E;
    #pragma unroll 1
    for (int tt = 0; tt < 16; ++tt) {
      float4 u4 = *(const float4*)(up + 4 * tt);
      #pragma unroll
      for (int q = 0; q < 4; ++q) {
        int t = 4 * tt + q;
        float uv = (q == 0) ? u4.x : (q == 1) ? u4.y : (q == 2) ? u4.z : u4.w;
        int pc = (int)__popc(sdtm[t] ^ w6);
        float dv = softplusf(biasd + sdv * (float)(RR - 2 * pc));
        S += dv;
        float du = dv * uv;
        #pragma unroll
        for (int g = 0; g < 4; ++g) {
          float4 bv = sB4[t * 4 + g];
          float a0 = exp2f(dv * An[4 * g + 0]);
          float a1 = exp2f(dv * An[4 * g + 1]);
          float a2 = exp2f(dv * An[4 * g + 2]);
          float a3 = exp2f(dv * An[4 * g + 3]);
          h[4 * g + 0] = a0 * h[4 * g + 0] + du * bv.x;
          h[4 * g + 1] = a1 * h[4 * g + 1] + du * bv.y;
          h[4 * g + 2] = a2 * h[4 * g + 2] + du * bv.z;
          h[4 * g + 3] = a3 * h[4 * g + 3] + du * bv.w;
        }
      }
    }
  }
  float* hp = hend + (size_t)c * 49152 + (size_t)(bk * DN + d) * 16;
  #pragma unroll
  for (int n = 0; n < NN; n += 4)
    *(float4*)(hp + n) = make_float4(h[n], h[n + 1], h[n + 2], h[n + 3]);
  Ssum[c * 3072 + bk * DN + d] = S;
}

// ---------------- scan pass B ----------------
__global__ __launch_bounds__(256) void k_scan_b(
    const float* __restrict__ A_logs, const float* __restrict__ Ssum,
    float* __restrict__ hend) {
  int tid = blockIdx.x * 256 + threadIdx.x;
  int bkd = tid >> 4, n = tid & 15;
  int bk = bkd / DN, d = bkd - bk * DN;
  int k = bk & 3;
  float An2 = -expf(A_logs[(k * DN + d) * NN + n]) * LOG2E;
  float h = 0.f;
  float Sc = Ssum[bkd];
  float he = hend[tid];
  #pragma unroll 1
  for (int c = 0; c < 64; ++c) {
    float Sn = 0.f, hn = 0.f;
    if (c < 63) {
      Sn = Ssum[(c + 1) * 3072 + bkd];
      hn = hend[(size_t)(c + 1) * 49152 + tid];
    }
    hend[(size_t)c * 49152 + tid] = h;
    h = exp2f(An2 * Sc) * h + he;
    Sc = Sn; he = hn;
  }
}

// ---------------- scan pass C ----------------
__global__ __launch_bounds__(192) void k_scan_c(
    const float* __restrict__ xs, const float* __restrict__ xdbl,
    const float* __restrict__ ws, const float* __restrict__ bd,
    const float* __restrict__ dt_bias, const float* __restrict__ A_logs,
    const float* __restrict__ Ds, const float* __restrict__ h0buf,
    float* __restrict__ y) {
  int c = blockIdx.x & 63;
  int bk = blockIdx.x >> 6;
  int k = bk & 3;
  int d = threadIdx.x;
  int t0 = c << 6;
  __shared__ uint32_t sdtm[64];
  __shared__ float4 sB4[256];
  __shared__ float4 sC4[256];
  float* sBf = (float*)sB4;
  float* sCf = (float*)sC4;
  const float* dtbase = xdbl + (size_t)bk * (RN * LL);
  if (d < 64) {
    const float2* p2 = (const float2*)(dtbase + t0 * 6 + d * 6);
    float2 a = p2[0], bb = p2[1], cc = p2[2];
    uint32_t m = (a.x > 0.f ? 1u : 0u) | (a.y > 0.f ? 2u : 0u) |
                 (bb.x > 0.f ? 4u : 0u) | (bb.y > 0.f ? 8u : 0u) |
                 (cc.x > 0.f ? 16u : 0u) | (cc.y > 0.f ? 32u : 0u);
    sdtm[d] = m;
  }
  {
    const float4* Bp = (const float4*)(xdbl + ((size_t)bk * RN + RR) * LL);
    const float4* Cp = (const float4*)(xdbl + ((size_t)bk * RN + RR + NN) * LL);
    for (int i = d; i < 256; i += 192) {
      int n = i >> 4, j = i & 15;
      float4 v = Bp[n * 1024 + (t0 >> 2) + j];
      sBf[(4 * j + 0) * 16 + n] = v.x;
      sBf[(4 * j + 1) * 16 + n] = v.y;
      sBf[(4 * j + 2) * 16 + n] = v.z;
      sBf[(4 * j + 3) * 16 + n] = v.w;
      float4 w = Cp[n * 1024 + (t0 >> 2) + j];
      sCf[(4 * j + 0) * 16 + n] = w.x;
      sCf[(4 * j + 1) * 16 + n] = w.y;
      sCf[(4 * j + 2) * 16 + n] = w.z;
      sCf[(4 * j + 3) * 16 + n] = w.w;
    }
  }
  uint32_t w6 = ((const uint32_t*)(ws + OFF_WDB))[k * DN + d];
  float sdv = (ws + OFF_WDB)[768 + k * DN + d];
  float biasd = bd[k * DN + d] + dt_bias[k * DN + d];
  float Dd = Ds[k * DN + d];
  float Araw[16];
  bool fok = true;
  {
    const float* ap = A_logs + (k * DN + d) * NN;
    #pragma unroll
    for (int n = 0; n < NN; ++n) {
      Araw[n] = -expf(ap[n]);
      fok = fok && (fabsf(Araw[n] + (float)(n + 1)) < 1e-3f);
    }
  }
  bool fastpath = (__ballot(fok) == ~0ull);
  float h[16];
  {
    const float* hp = h0buf + (size_t)c * 49152 + (size_t)(bk * DN + d) * 16;
    #pragma unroll
    for (int n = 0; n < NN; n += 4) {
      float4 v = *(const float4*)(hp + n);
      h[n] = v.x; h[n + 1] = v.y; h[n + 2] = v.z; h[n + 3] = v.w;
    }
  }
  const float* up = xs + ((size_t)bk * DN + d) * LL + t0;
  float* yb = y + (size_t)(bk >> 2) * (LL * DN);
  __syncthreads();
  if (fastpath) {
    #pragma unroll 1
    for (int tt = 0; tt < 16; ++tt) {
      float4 u4 = *(const float4*)(up + 4 * tt);
      #pragma unroll
      for (int q = 0; q < 4; ++q) {
        int t = 4 * tt + q;
        float uv = (q == 0) ? u4.x : (q == 1) ? u4.y : (q == 2) ? u4.z : u4.w;
        int pc = (int)__popc(sdtm[t] ^ w6);
        float dv = softplusf(biasd + sdv * (float)(RR - 2 * pc));
        float rr = exp2f(-dv * LOG2E);
        float du = dv * uv;
        float yv = Dd * uv;
        float a[16];
        rpowers(rr, a);
        #pragma unroll
        for (int g = 0; g < 4; ++g) {
          float4 bv = sB4[t * 4 + g];
          float4 cv = sC4[t * 4 + g];
          h[4 * g + 0] = a[4 * g + 0] * h[4 * g + 0] + du * bv.x;
          h[4 * g + 1] = a[4 * g + 1] * h[4 * g + 1] + du * bv.y;
          h[4 * g + 2] = a[4 * g + 2] * h[4 * g + 2] + du * bv.z;
          h[4 * g + 3] = a[4 * g + 3] * h[4 * g + 3] + du * bv.w;
          yv += cv.x * h[4 * g + 0];
          yv += cv.y * h[4 * g + 1];
          yv += cv.z * h[4 * g + 2];
          yv += cv.w * h[4 * g + 3];
        }
        int ta = t0 + t, l;
        if (k == 0)      l = ta;
        else if (k == 1) l = ((ta & 63) << 6) | (ta >> 6);
        else if (k == 2) l = 4095 - ta;
        else { int t2 = 4095 - ta; l = ((t2 & 63) << 6) | (t2 >> 6); }
        atomicAdd(&yb[(size_t)l * DN + d], yv);
      }
    }
  } else {
    float An[16];
    #pragma unroll
    for (int n = 0; n < NN; ++n) An[n] = Araw[n] * LOG2E;
    #pragma unroll 1
    for (int tt = 0; tt < 16; ++tt) {
      float4 u4 = *(const float4*)(up + 4 * tt);
      #pragma unroll
      for (int q = 0; q < 4; ++q) {
        int t = 4 * tt + q;
        float uv = (q == 0) ? u4.x : (q == 1) ? u4.y : (q == 2) ? u4.z : u4.w;
        int pc = (int)__popc(sdtm[t] ^ w6);
        float dv = softplusf(biasd + sdv * (float)(RR - 2 * pc));
        float du = dv * uv;
        float yv = Dd * uv;
        #pragma unroll
        for (int g = 0; g < 4; ++g) {
          float4 bv = sB4[t * 4 + g];
          float4 cv = sC4[t * 4 + g];
          float a0 = exp2f(dv * An[4 * g + 0]);
          float a1 = exp2f(dv * An[4 * g + 1]);
          float a2 = exp2f(dv * An[4 * g + 2]);
          float a3 = exp2f(dv * An[4 * g + 3]);
          h[4 * g + 0] = a0 * h[4 * g + 0] + du * bv.x;
          h[4 * g + 1] = a1 * h[4 * g + 1] + du * bv.y;
          h[4 * g + 2] = a2 * h[4 * g + 2] + du * bv.z;
          h[4 * g + 3] = a3 * h[4 * g + 3] + du * bv.w;
          yv += cv.x * h[4 * g + 0];
          yv += cv.y * h[4 * g + 1];
          yv += cv.z * h[4 * g + 2];
          yv += cv.w * h[4 * g + 3];
        }
        int ta = t0 + t, l;
        if (k == 0)      l = ta;
        else if (k == 1) l = ((ta & 63) << 6) | (ta >> 6);
        else if (k == 2) l = 4095 - ta;
        else { int t2 = 4095 - ta; l = ((t2 & 63) << 6) | (t2 >> 6); }
        atomicAdd(&yb[(size_t)l * DN + d], yv);
      }
    }
  }
}

// ---------------- LayerNorm over Dn + * silu(z) -> packed sign bits ----------------
__global__ __launch_bounds__(256) void k_ln(
    const float* __restrict__ y, const float* __restrict__ zs,
    const float* __restrict__ ln_w, const float* __restrict__ ln_b,
    uint32_t* __restrict__ ybits) {
  __shared__ float ty[64 * 193];
  __shared__ float ps[256];
  __shared__ float smu[64], srs[64];
  __shared__ float slw[DN], slb[DN];
  int b = blockIdx.x >> 6;
  int l0 = (blockIdx.x & 63) << 6;
  const float* yp = y + (size_t)(b * LL + l0) * DN;
  if (threadIdx.x < DN) {
    slw[threadIdx.x] = ln_w[threadIdx.x];
    slb[threadIdx.x] = ln_b[threadIdx.x];
  }
  {
    int lc = threadIdx.x / DN, d2 = threadIdx.x - lc * DN;
    for (int i = threadIdx.x; i < 64 * DN; i += 256) {
      ty[lc * 193 + d2] = yp[i];
      d2 += 256;
      if (d2 >= DN) { d2 -= DN; lc += 1; if (d2 >= DN) { d2 -= DN; lc += 1; } }
    }
  }
  __syncthreads();
  int lc = threadIdx.x & 63, part = threadIdx.x >> 6;
  float s = 0.f;
  for (int d = part * 48; d < part * 48 + 48; ++d) s += ty[lc * 193 + d];
  ps[threadIdx.x] = s;
  __syncthreads();
  if (threadIdx.x < 64)
    smu[threadIdx.x] = (ps[threadIdx.x] + ps[threadIdx.x + 64] +
                        ps[threadIdx.x + 128] + ps[threadIdx.x + 192]) / (float)DN;
  __syncthreads();
  float mu = smu[lc];
  float q = 0.f;
  for (int d = part * 48; d < part * 48 + 48; ++d) {
    float v = ty[lc * 193 + d] - mu; q += v * v;
  }
  ps[threadIdx.x] = q;
  __syncthreads();
  if (threadIdx.x < 64) {
    float var = (ps[threadIdx.x] + ps[threadIdx.x + 64] +
                 ps[threadIdx.x + 128] + ps[threadIdx.x + 192]) / (float)DN;
    srs[threadIdx.x] = rsqrtf(var + 1e-5f);
  }
  __syncthreads();
  for (int item = threadIdx.x; item < 64 * 6; item += 256) {
    int lc2 = item / 6, wd = item % 6;
    float mu2 = smu[lc2], rs2 = srs[lc2];
    const float* zb = zs + (size_t)(b * LL + l0 + lc2) * DN + wd * 32;
    uint32_t wv = 0;
    #pragma unroll
    for (int i = 0; i < 32; ++i) {
      int d = wd * 32 + i;
      float ln = (ty[lc2 * 193 + d] - mu2) * rs2 * slw[d] + slb[d];
      wv |= ((ln * zb[i] > 0.f) ? 1u : 0u) << i;
    }
    ybits[(size_t)(b * LL + l0 + lc2) * 6 + wd] = wv;
  }
}

// ---------------- output bilinear via XOR-popcount ----------------
__global__ __launch_bounds__(256) void k_out(
    const uint32_t* __restrict__ ybits, const float* __restrict__ ws,
    const float* __restrict__ b_out, const float* __restrict__ s_out,
    float* __restrict__ out) {
  __shared__ uint32_t sy[64 * 6];
  __shared__ uint32_t swo[96 * 6];
  __shared__ float sb[96], ssc[96];
  int p0 = blockIdx.x * 64;
  for (int i = threadIdx.x; i < 64 * 6; i += 256) sy[i] = ybits[(size_t)p0 * 6 + i];
  for (int i = threadIdx.x; i < 96 * 6; i += 256) swo[i] = ((const uint32_t*)(ws + OFF_WOUTB))[i];
  if (threadIdx.x < 96) {
    sb[threadIdx.x] = b_out[threadIdx.x];
    ssc[threadIdx.x] = s_out[threadIdx.x];
  }
  __syncthreads();
  for (int oi = threadIdx.x; oi < 64 * DM; oi += 256) {
    int pr = oi / DM, m = oi % DM;
    int P = 0;
    #pragma unroll
    for (int j = 0; j < 6; ++j) P += (int)__popc(sy[pr * 6 + j] ^ swo[m * 6 + j]);
    out[(size_t)(p0 + pr) * DM + m] = sb[m] + ssc[m] * (float)(DN - 2 * P);
  }
}

extern "C" void kernel_launch(void* const* d_in, const int* in_sizes, int n_in,
                              void* d_out, int out_size, void* d_ws, size_t ws_size,
                              hipStream_t stream) {
  const float* x       = (const float*)d_in[0];
  const float* W_in    = (const float*)d_in[1];
  const float* b_in    = (const float*)d_in[2];
  const float* s_in    = (const float*)d_in[3];
  const float* move0_b = (const float*)d_in[4];
  const float* conv_W  = (const float*)d_in[5];
  const float* conv_b  = (const float*)d_in[6];
  const float* rp_b0   = (const float*)d_in[7];
  const float* prelu_a = (const float*)d_in[8];
  const float* rp_b1   = (const float*)d_in[9];
  const float* Wl      = (const float*)d_in[10];
  const float* bl      = (const float*)d_in[11];
  const float* sl      = (const float*)d_in[12];
  const float* Wd      = (const float*)d_in[13];
  const float* bd      = (const float*)d_in[14];
  const float* sd      = (const float*)d_in[15];
  const float* dt_bias = (const float*)d_in[16];
  const float* A_logs  = (const float*)d_in[17];
  const float* Ds      = (const float*)d_in[18];
  const float* ln_w    = (const float*)d_in[19];
  const float* ln_b    = (const float*)d_in[20];
  const float* W_out   = (const float*)d_in[21];
  const float* b_out   = (const float*)d_in[22];
  const float* s_out   = (const float*)d_in[23];
  float* ws  = (float*)d_ws;
  float* out = (float*)d_out;

  hipLaunchKernelGGL(k_prep, dim3(1592), dim3(64), 0, stream,
                     W_in, s_in, W_out, s_out, Wl, sl, Wd, sd, conv_W, ws);
  hipLaunchKernelGGL(k_bilin_in, dim3(1024), dim3(384), 0, stream,
                     x, b_in, s_in, ws, ws + OFF_XC, ws + OFF_ZS);
  hipMemsetAsync((void*)(ws + OFF_XBP), 0, (size_t)(4 * 6 * PLANE) * 4, stream);
  hipLaunchKernelGGL(k_pack, dim3(192), dim3(256), 0, stream,
                     ws + OFF_XC, move0_b, (uint32_t*)(ws + OFF_XBP));
  hipLaunchKernelGGL(k_conv, dim3(256), dim3(256), 0, stream,
                     (const uint32_t*)(ws + OFF_XBP), ws + OFF_XC,
                     (const uint32_t*)(ws + OFF_WCS), (const int*)(ws + OFF_WAUX),
                     ws + OFF_WSC, conv_b, rp_b0, prelu_a, rp_b1,
                     ws + OFF_XCONV);
  hipLaunchKernelGGL(k_build_xs, dim3(768), dim3(256), 0, stream,
                     ws + OFF_XCONV, ws + OFF_XS, (uint32_t*)(ws + OFF_PXS));
  hipLaunchKernelGGL(k_xdbl, dim3(256), dim3(256), 0, stream,
                     (const uint32_t*)(ws + OFF_PXS), ws, bl, sl, ws + OFF_XDBL);
  hipLaunchKernelGGL(k_scan_a, dim3(1024), dim3(192), 0, stream,
                     ws + OFF_XS, ws + OFF_XDBL, ws, bd, dt_bias, A_logs,
                     ws + OFF_HEND, ws + OFF_SSUM);
  hipLaunchKernelGGL(k_scan_b, dim3(192), dim3(256), 0, stream,
                     A_logs, ws + OFF_SSUM, ws + OFF_HEND);
  hipMemsetAsync((void*)(ws + OFF_XC), 0, (size_t)3145728 * sizeof(float), stream);
  hipLaunchKernelGGL(k_scan_c, dim3(1024), dim3(192), 0, stream,
                     ws + OFF_XS, ws + OFF_XDBL, ws, bd, dt_bias, A_logs, Ds,
                     ws + OFF_HEND, ws + OFF_XC);
  hipLaunchKernelGGL(k_ln, dim3(256), dim3(256), 0, stream,
                     ws + OFF_XC, ws + OFF_ZS, ln_w, ln_b, (uint32_t*)(ws + OFF_YB));
  hipLaunchKernelGGL(k_out, dim3(256), dim3(256), 0, stream,
                     (const uint32_t*)(ws + OFF_YB), ws, b_out, s_out, out);
}